// Round 1
// baseline (503.918 us; speedup 1.0000x reference)
//
#include <hip/hip_runtime.h>
#include <stdint.h>

// N=16384, M=16, DIST=2, HEADS=8, D=256, C=64, DFFN=512, DH=32, GRID=128
static constexpr int kN = 16384;
static constexpr float kEPS = 1e-5f;

// ---------------- neighbor grid (cells = x*128+y) ----------------

__global__ __launch_bounds__(256) void k_hist(const int* __restrict__ coords,
                                              uint32_t* __restrict__ cnt) {
  int n = blockIdx.x * 256 + threadIdx.x;
  int c = coords[n * 3] * 128 + coords[n * 3 + 1];
  atomicAdd(&cnt[c], 1u);
}

__global__ __launch_bounds__(256) void k_scan(const uint32_t* __restrict__ cnt,
                                              uint32_t* __restrict__ startb) {
  __shared__ uint32_t tots[256];
  int t = threadIdx.x;
  int base = t * 64;
  uint32_t s = 0;
  for (int i = 0; i < 64; i++) s += cnt[base + i];
  tots[t] = s;
  __syncthreads();
  if (t == 0) {
    uint32_t run = 0;
    for (int i = 0; i < 256; i++) { uint32_t v = tots[i]; tots[i] = run; run += v; }
  }
  __syncthreads();
  uint32_t run = tots[t];
  for (int i = 0; i < 64; i++) { startb[base + i] = run; run += cnt[base + i]; }
}

__global__ __launch_bounds__(256) void k_scatter(const int* __restrict__ coords,
                                                 const uint32_t* __restrict__ startb,
                                                 uint32_t* __restrict__ cursor,
                                                 uint32_t* __restrict__ pts) {
  int n = blockIdx.x * 256 + threadIdx.x;
  int x = coords[n * 3], y = coords[n * 3 + 1], z = coords[n * 3 + 2];
  int c = x * 128 + y;
  uint32_t slot = atomicAdd(&cursor[c], 1u);
  pts[startb[c] + slot] = ((uint32_t)z << 14) | (uint32_t)n;  // z:7b | idx:14b
}

// top-16 by exact (dist, index) ascending — matches jax.lax.top_k tie rules
__global__ __launch_bounds__(256) void k_select(const int* __restrict__ coords,
                                                const uint32_t* __restrict__ startb,
                                                const uint32_t* __restrict__ cnt,
                                                const uint32_t* __restrict__ pts,
                                                int* __restrict__ idxo) {
  int n = blockIdx.x * 256 + threadIdx.x;
  int x = coords[n * 3], y = coords[n * 3 + 1], z = coords[n * 3 + 2];
  uint32_t best[16];
#pragma unroll
  for (int j = 0; j < 16; j++) best[j] = 0xFFFFFFFFu;
  const int dxs[13] = {0, -1, 1, 0, 0, -2, 2, 0, 0, -1, -1, 1, 1};
  const int dys[13] = {0, 0, 0, -1, 1, 0, 0, -2, 2, -1, 1, -1, 1};
  const int dbs[13] = {0, 1, 1, 1, 1, 2, 2, 2, 2, 2, 2, 2, 2};
#pragma unroll
  for (int t = 0; t < 13; t++) {
    int xx = x + dxs[t], yy = y + dys[t];
    if (xx < 0 || xx > 127 || yy < 0 || yy > 127) continue;
    int c = xx * 128 + yy;
    uint32_t s0 = startb[c], e0 = s0 + cnt[c];
    for (uint32_t i = s0; i < e0; ++i) {
      uint32_t p = pts[i];
      int zq = (int)(p >> 14);
      int id = (int)(p & 16383u);
      int az = z - zq; az = az < 0 ? -az : az;
      int dd = dbs[t] + az;
      uint32_t key = (dd <= 2) ? (((uint32_t)dd << 14) | (uint32_t)id) : 0xFFFFFFFFu;
#pragma unroll
      for (int j = 0; j < 16; j++) {
        uint32_t lo = min(best[j], key);
        uint32_t hi = max(best[j], key);
        best[j] = lo; key = hi;
      }
    }
  }
#pragma unroll
  for (int j = 0; j < 16; j++)
    idxo[n * 16 + j] = (best[j] == 0xFFFFFFFFu) ? -1 : (int)(best[j] & 16383u);
}

// ---------------- src = features@proj_w + proj_b + PE(coords) ----------------
// 16 rows per block, 256 threads (one output dim each)
__global__ __launch_bounds__(256) void k_src(const int* __restrict__ coords,
                                             const float* __restrict__ feats,
                                             const float* __restrict__ pw1,
                                             const float* __restrict__ pb1,
                                             const float* __restrict__ pw2,
                                             const float* __restrict__ pb2,
                                             const float* __restrict__ projw,
                                             const float* __restrict__ projb,
                                             float* __restrict__ src) {
  __shared__ float sf[16][64];
  __shared__ float sh[16][128];
  int r0 = blockIdx.x * 16;
  int tid = threadIdx.x;
  {
    int e = tid * 4, r = e >> 6, c = e & 63;
    *(float4*)&sf[r][c] = *(const float4*)(feats + (r0 + r) * 64 + c);
  }
  {
    int j = tid & 127, half = tid >> 7;
#pragma unroll
    for (int rr = 0; rr < 8; rr++) {
      int r = half * 8 + rr;
      float x0 = (float)coords[(r0 + r) * 3 + 0] * (1.f / 127.f);
      float x1 = (float)coords[(r0 + r) * 3 + 1] * (1.f / 127.f);
      float x2 = (float)coords[(r0 + r) * 3 + 2] * (1.f / 127.f);
      float hv = pb1[j] + x0 * pw1[j] + x1 * pw1[128 + j] + x2 * pw1[256 + j];
      sh[r][j] = fmaxf(hv, 0.f);
    }
  }
  __syncthreads();
  int d = tid;
  float acc[16];
  float pb = projb[d] + pb2[d];
#pragma unroll
  for (int r = 0; r < 16; r++) acc[r] = pb;
  for (int c = 0; c < 64; c++) {
    float w = projw[c * 256 + d];
#pragma unroll
    for (int r = 0; r < 16; r++) acc[r] += sf[r][c] * w;
  }
  for (int j = 0; j < 128; j++) {
    float w = pw2[j * 256 + d];
#pragma unroll
    for (int r = 0; r < 16; r++) acc[r] += sh[r][j] * w;
  }
#pragma unroll
  for (int r = 0; r < 16; r++) src[(r0 + r) * 256 + d] = acc[r];
}

// ---------------- generic fp32 GEMM: C = A@W (+bias) (+relu) ----------------
// BM=BN=64, BK=16, 256 threads, 4x4 per thread
template <int ACT>
__global__ __launch_bounds__(256) void k_gemm(const float* __restrict__ A,
                                              const float* __restrict__ Wm,
                                              const float* __restrict__ bias,
                                              float* __restrict__ C,
                                              int M, int K, int Nn) {
  __shared__ float As[16][64];
  __shared__ float Bs[16][64];
  const int tid = threadIdx.x;
  const int bm = blockIdx.y * 64, bn = blockIdx.x * 64;
  const int tx = tid & 15, ty = tid >> 4;
  float acc[4][4];
#pragma unroll
  for (int i = 0; i < 4; i++)
#pragma unroll
    for (int j = 0; j < 4; j++) acc[i][j] = 0.f;
  const int ar = tid >> 2, ak = (tid & 3) * 4;
  const int wk_ = tid >> 4, wn = (tid & 15) * 4;
  for (int k0 = 0; k0 < K; k0 += 16) {
    float4 av = *(const float4*)(A + (bm + ar) * K + k0 + ak);
    As[ak + 0][ar] = av.x; As[ak + 1][ar] = av.y;
    As[ak + 2][ar] = av.z; As[ak + 3][ar] = av.w;
    float4 wv = *(const float4*)(Wm + (k0 + wk_) * Nn + bn + wn);
    *(float4*)&Bs[wk_][wn] = wv;
    __syncthreads();
#pragma unroll
    for (int k = 0; k < 16; k++) {
      float4 a = *(const float4*)&As[k][ty * 4];
      float4 b = *(const float4*)&Bs[k][tx * 4];
      acc[0][0] += a.x * b.x; acc[0][1] += a.x * b.y; acc[0][2] += a.x * b.z; acc[0][3] += a.x * b.w;
      acc[1][0] += a.y * b.x; acc[1][1] += a.y * b.y; acc[1][2] += a.y * b.z; acc[1][3] += a.y * b.w;
      acc[2][0] += a.z * b.x; acc[2][1] += a.z * b.y; acc[2][2] += a.z * b.z; acc[2][3] += a.z * b.w;
      acc[3][0] += a.w * b.x; acc[3][1] += a.w * b.y; acc[3][2] += a.w * b.z; acc[3][3] += a.w * b.w;
    }
    __syncthreads();
  }
  float4 bb = make_float4(0.f, 0.f, 0.f, 0.f);
  if (bias) bb = *(const float4*)(bias + bn + tx * 4);
#pragma unroll
  for (int i = 0; i < 4; i++) {
    int row = bm + ty * 4 + i;
    float4 o;
    o.x = acc[i][0] + bb.x; o.y = acc[i][1] + bb.y;
    o.z = acc[i][2] + bb.z; o.w = acc[i][3] + bb.w;
    if (ACT) {
      o.x = fmaxf(o.x, 0.f); o.y = fmaxf(o.y, 0.f);
      o.z = fmaxf(o.z, 0.f); o.w = fmaxf(o.w, 0.f);
    }
    *(float4*)(C + row * Nn + bn + tx * 4) = o;
  }
}

// ---------------- attention: one thread per (n, head) ----------------
// invalid slot: k = bk (score = q.bk/sqrt(32)), v = bv — still in softmax.
__global__ __launch_bounds__(256) void k_attn(const float* __restrict__ Q,
                                              const float* __restrict__ Kk,
                                              const float* __restrict__ V,
                                              const int* __restrict__ idx,
                                              const float* __restrict__ bq,
                                              const float* __restrict__ bk,
                                              const float* __restrict__ bv,
                                              float* __restrict__ outp) {
  int gid = blockIdx.x * 256 + threadIdx.x;
  int n = gid >> 3, h = gid & 7;
  const int* ip = idx + n * 16;
  const int hb = h * 32;
  float q[32];
  {
    int i0 = ip[0];  // slot0 always valid (self, d=0)
    const float* qp = Q + i0 * 256 + hb;
#pragma unroll
    for (int j = 0; j < 32; j += 4) {
      float4 a = *(const float4*)(qp + j);
      float4 b = *(const float4*)(bq + hb + j);
      q[j] = a.x + b.x; q[j + 1] = a.y + b.y; q[j + 2] = a.z + b.z; q[j + 3] = a.w + b.w;
    }
  }
  float qbk = 0.f;
#pragma unroll
  for (int j = 0; j < 32; j += 4) {
    float4 b = *(const float4*)(bk + hb + j);
    qbk += q[j] * b.x + q[j + 1] * b.y + q[j + 2] * b.z + q[j + 3] * b.w;
  }
  float s[16]; int ii[16];
#pragma unroll
  for (int m = 0; m < 16; m++) {
    int i = ip[m]; ii[m] = i;
    float d = qbk;
    if (i >= 0) {
      const float* kp = Kk + i * 256 + hb;
#pragma unroll
      for (int j = 0; j < 32; j += 4) {
        float4 kv = *(const float4*)(kp + j);
        d += q[j] * kv.x + q[j + 1] * kv.y + q[j + 2] * kv.z + q[j + 3] * kv.w;
      }
    }
    s[m] = d * 0.17677669529663689f;  // 1/sqrt(32)
  }
  float mx = s[0];
#pragma unroll
  for (int m = 1; m < 16; m++) mx = fmaxf(mx, s[m]);
  float sum = 0.f;
#pragma unroll
  for (int m = 0; m < 16; m++) { s[m] = __expf(s[m] - mx); sum += s[m]; }
  float inv = 1.f / sum;
  float o[32];
#pragma unroll
  for (int j = 0; j < 32; j++) o[j] = 0.f;
#pragma unroll
  for (int m = 0; m < 16; m++) {
    if (ii[m] >= 0) {
      const float* vp = V + ii[m] * 256 + hb;
#pragma unroll
      for (int j = 0; j < 32; j += 4) {
        float4 vv = *(const float4*)(vp + j);
        o[j] += s[m] * vv.x; o[j + 1] += s[m] * vv.y;
        o[j + 2] += s[m] * vv.z; o[j + 3] += s[m] * vv.w;
      }
    }
  }
  float* op = outp + n * 256 + hb;
#pragma unroll
  for (int j = 0; j < 32; j += 4) {
    float4 b = *(const float4*)(bv + hb + j);
    float4 ov;
    ov.x = o[j] * inv + b.x; ov.y = o[j + 1] * inv + b.y;
    ov.z = o[j + 2] * inv + b.z; ov.w = o[j + 3] * inv + b.w;
    *(float4*)(op + j) = ov;
  }
}

// ---------------- layernorm over D=256 of (ao + h), one wave per row ----------------
__global__ __launch_bounds__(256) void k_ln(const float* __restrict__ ao,
                                            const float* __restrict__ hh,
                                            const float* __restrict__ g,
                                            const float* __restrict__ b,
                                            float* __restrict__ y) {
  int row = blockIdx.x * 4 + (threadIdx.x >> 6);
  int lane = threadIdx.x & 63;
  float4 a = *(const float4*)(ao + row * 256 + lane * 4);
  float4 h4 = *(const float4*)(hh + row * 256 + lane * 4);
  float x0 = a.x + h4.x, x1 = a.y + h4.y, x2 = a.z + h4.z, x3 = a.w + h4.w;
  float sm = x0 + x1 + x2 + x3;
#pragma unroll
  for (int off = 1; off < 64; off <<= 1) sm += __shfl_xor(sm, off);
  float mu = sm * (1.f / 256.f);
  float d0 = x0 - mu, d1 = x1 - mu, d2 = x2 - mu, d3 = x3 - mu;
  float sq = d0 * d0 + d1 * d1 + d2 * d2 + d3 * d3;
#pragma unroll
  for (int off = 1; off < 64; off <<= 1) sq += __shfl_xor(sq, off);
  float rstd = rsqrtf(sq * (1.f / 256.f) + kEPS);
  float4 gv = *(const float4*)(g + lane * 4);
  float4 bv4 = *(const float4*)(b + lane * 4);
  float4 o;
  o.x = d0 * rstd * gv.x + bv4.x; o.y = d1 * rstd * gv.y + bv4.y;
  o.z = d2 * rstd * gv.z + bv4.z; o.w = d3 * rstd * gv.w + bv4.w;
  *(float4*)(y + row * 256 + lane * 4) = o;
}

// ---------------- concat [features | t] -> (N,128) ----------------
__global__ __launch_bounds__(256) void k_cat(const float* __restrict__ feats,
                                             const float* __restrict__ t,
                                             float* __restrict__ cat) {
  int gid = blockIdx.x * 256 + threadIdx.x;
  int e = gid * 4, n = e >> 7, c = e & 127;
  float4 v = (c < 64) ? *(const float4*)(feats + n * 64 + c)
                      : *(const float4*)(t + n * 64 + (c - 64));
  *(float4*)(cat + e) = v;
}

// ---------------- batchnorm over N: partial sums -> finalize -> apply+relu ----------------
__global__ __launch_bounds__(256) void k_stats(const float* __restrict__ f,
                                               float* __restrict__ pS, float* __restrict__ pQ) {
  int col = threadIdx.x & 63, rc = threadIdx.x >> 6;
  int r0 = blockIdx.x * 128 + rc * 32;
  float s = 0.f, q = 0.f;
  for (int r = 0; r < 32; r++) {
    float v = f[(r0 + r) * 64 + col];
    s += v; q += v * v;
  }
  __shared__ float ls[4][64], lq[4][64];
  ls[rc][col] = s; lq[rc][col] = q;
  __syncthreads();
  if (rc == 0) {
    s = ls[0][col] + ls[1][col] + ls[2][col] + ls[3][col];
    q = lq[0][col] + lq[1][col] + lq[2][col] + lq[3][col];
    pS[blockIdx.x * 64 + col] = s;
    pQ[blockIdx.x * 64 + col] = q;
  }
}

__global__ __launch_bounds__(64) void k_bnfin(const float* __restrict__ pS,
                                              const float* __restrict__ pQ,
                                              const float* __restrict__ g,
                                              const float* __restrict__ b,
                                              float* __restrict__ coef,
                                              float* __restrict__ shift) {
  int c = threadIdx.x;
  float s = 0.f, q = 0.f;
  for (int i = 0; i < 128; i++) { s += pS[i * 64 + c]; q += pQ[i * 64 + c]; }
  float mu = s * (1.f / 16384.f);
  float var = q * (1.f / 16384.f) - mu * mu;
  float cf = rsqrtf(var + kEPS) * g[c];
  coef[c] = cf;
  shift[c] = b[c] - mu * cf;
}

__global__ __launch_bounds__(256) void k_bnapply(const float* __restrict__ f,
                                                 const float* __restrict__ coef,
                                                 const float* __restrict__ shift,
                                                 float* __restrict__ out) {
  int gid = blockIdx.x * 256 + threadIdx.x;
  int e = gid * 4, col = e & 63;
  float4 v = *(const float4*)(f + e);
  float4 cf = *(const float4*)(coef + col);
  float4 sh = *(const float4*)(shift + col);
  float4 o;
  o.x = fmaxf(v.x * cf.x + sh.x, 0.f);
  o.y = fmaxf(v.y * cf.y + sh.y, 0.f);
  o.z = fmaxf(v.z * cf.z + sh.z, 0.f);
  o.w = fmaxf(v.w * cf.w + sh.w, 0.f);
  *(float4*)(out + e) = o;
}

// ---------------- launch ----------------
extern "C" void kernel_launch(void* const* d_in, const int* in_sizes, int n_in,
                              void* d_out, int out_size, void* d_ws, size_t ws_size,
                              hipStream_t stream) {
  (void)in_sizes; (void)n_in; (void)out_size; (void)ws_size;
  const int*   coords = (const int*)d_in[0];
  const float* feats  = (const float*)d_in[1];
  const float* pe_w1  = (const float*)d_in[2];
  const float* pe_b1  = (const float*)d_in[3];
  const float* pe_w2  = (const float*)d_in[4];
  const float* pe_b2  = (const float*)d_in[5];
  const float* proj_w = (const float*)d_in[6];
  const float* proj_b = (const float*)d_in[7];
  const float* wq  = (const float*)d_in[8];
  const float* bq  = (const float*)d_in[9];
  const float* wk  = (const float*)d_in[10];
  const float* bk  = (const float*)d_in[11];
  const float* wv  = (const float*)d_in[12];
  const float* bv  = (const float*)d_in[13];
  const float* wo  = (const float*)d_in[14];
  const float* bo  = (const float*)d_in[15];
  const float* fw1 = (const float*)d_in[16];
  const float* fb1 = (const float*)d_in[17];
  const float* fw2 = (const float*)d_in[18];
  const float* fb2 = (const float*)d_in[19];
  const float* lng = (const float*)d_in[20];
  const float* lnb = (const float*)d_in[21];
  const float* uw1 = (const float*)d_in[22];
  const float* ub1 = (const float*)d_in[23];
  const float* uw2 = (const float*)d_in[24];
  const float* ub2 = (const float*)d_in[25];
  const float* bng = (const float*)d_in[26];
  const float* bnb = (const float*)d_in[27];
  float* out = (float*)d_out;

  // workspace layout (floats). total ~102 MB
  float* W  = (float*)d_ws;
  float* B0 = W;               // src, later attn-out      (N*256)
  float* B1 = W + 4194304;     // Q_all, later ao          (N*256)
  float* B2 = W + 8388608;     // K_all, later ffn-h       (N*256)
  float* B3 = W + 12582912;    // V_all, later y           (N*256)
  float* B4 = W + 16777216;    // ffn hidden (N*512); later t/cat/f
  float* tB   = B4;
  float* catB = B4 + 1048576;
  float* fB   = B4 + 3145728;
  uint32_t* cnt    = (uint32_t*)(W + 25165824);  // 16384
  uint32_t* cursor = cnt + 16384;
  uint32_t* startb = cnt + 32768;
  uint32_t* pts    = cnt + 49152;
  int*      idxb   = (int*)(cnt + 65536);        // N*16
  float* pS    = (float*)(cnt + 65536 + 262144);
  float* pQ    = pS + 8192;
  float* coefb = pQ + 8192;
  float* shb   = coefb + 64;

  hipMemsetAsync(cnt, 0, 32768 * sizeof(uint32_t), stream);  // cnt + cursor

  k_hist<<<64, 256, 0, stream>>>(coords, cnt);
  k_scan<<<1, 256, 0, stream>>>(cnt, startb);
  k_scatter<<<64, 256, 0, stream>>>(coords, startb, cursor, pts);
  k_select<<<64, 256, 0, stream>>>(coords, startb, cnt, pts, idxb);

  k_src<<<1024, 256, 0, stream>>>(coords, feats, pe_w1, pe_b1, pe_w2, pe_b2,
                                  proj_w, proj_b, B0);

  k_gemm<0><<<dim3(4, 256), 256, 0, stream>>>(B0, wq, nullptr, B1, kN, 256, 256);
  k_gemm<0><<<dim3(4, 256), 256, 0, stream>>>(B0, wk, nullptr, B2, kN, 256, 256);
  k_gemm<0><<<dim3(4, 256), 256, 0, stream>>>(B0, wv, nullptr, B3, kN, 256, 256);

  k_attn<<<512, 256, 0, stream>>>(B1, B2, B3, idxb, bq, bk, bv, B0);

  k_gemm<0><<<dim3(4, 256), 256, 0, stream>>>(B0, wo, bo, B1, kN, 256, 256);    // ao
  k_gemm<1><<<dim3(8, 256), 256, 0, stream>>>(B1, fw1, fb1, B4, kN, 256, 512);  // relu
  k_gemm<0><<<dim3(4, 256), 256, 0, stream>>>(B4, fw2, fb2, B2, kN, 512, 256);  // h

  k_ln<<<4096, 256, 0, stream>>>(B1, B2, lng, lnb, B3);                         // y

  k_gemm<0><<<dim3(1, 256), 256, 0, stream>>>(B3, uw1, ub1, tB, kN, 256, 64);   // t
  k_cat<<<2048, 256, 0, stream>>>(feats, tB, catB);
  k_gemm<0><<<dim3(1, 256), 256, 0, stream>>>(catB, uw2, ub2, fB, kN, 128, 64); // f

  k_stats<<<128, 256, 0, stream>>>(fB, pS, pQ);
  k_bnfin<<<1, 64, 0, stream>>>(pS, pQ, bng, bnb, coefb, shb);
  k_bnapply<<<1024, 256, 0, stream>>>(fB, coefb, shb, out);
}

// Round 2
// 316.836 us; speedup vs baseline: 1.5905x; 1.5905x over previous
//
#include <hip/hip_runtime.h>
#include <stdint.h>

typedef unsigned short u16;
typedef unsigned int   u32;
typedef __attribute__((ext_vector_type(8))) short short8;
typedef __attribute__((ext_vector_type(4))) float f32x4;

static constexpr int kN = 16384;
static constexpr float kEPS = 1e-5f;

__device__ __forceinline__ u16 f2bf(float x) {
  u32 u = __float_as_uint(x);
  u32 r = (u + 0x7fffu + ((u >> 16) & 1u)) >> 16;
  return (u16)r;
}
__device__ __forceinline__ void ldbf8(const u16* p, float* o) {
  uint4 v = *(const uint4*)p;
  o[0] = __uint_as_float(v.x << 16);  o[1] = __uint_as_float(v.x & 0xffff0000u);
  o[2] = __uint_as_float(v.y << 16);  o[3] = __uint_as_float(v.y & 0xffff0000u);
  o[4] = __uint_as_float(v.z << 16);  o[5] = __uint_as_float(v.z & 0xffff0000u);
  o[6] = __uint_as_float(v.w << 16);  o[7] = __uint_as_float(v.w & 0xffff0000u);
}

// ---------------- neighbor grid (cells = x*128+y) ----------------

__global__ __launch_bounds__(256) void k_hist(const int* __restrict__ coords,
                                              u32* __restrict__ cnt) {
  int n = blockIdx.x * 256 + threadIdx.x;
  int c = coords[n * 3] * 128 + coords[n * 3 + 1];
  atomicAdd(&cnt[c], 1u);
}

__global__ __launch_bounds__(256) void k_scan(const u32* __restrict__ cnt,
                                              u32* __restrict__ startb) {
  __shared__ u32 tots[256];
  int t = threadIdx.x;
  int base = t * 64;
  u32 s = 0;
  for (int i = 0; i < 64; i++) s += cnt[base + i];
  tots[t] = s;
  __syncthreads();
  if (t == 0) {
    u32 run = 0;
    for (int i = 0; i < 256; i++) { u32 v = tots[i]; tots[i] = run; run += v; }
  }
  __syncthreads();
  u32 run = tots[t];
  for (int i = 0; i < 64; i++) { startb[base + i] = run; run += cnt[base + i]; }
}

__global__ __launch_bounds__(256) void k_scatter(const int* __restrict__ coords,
                                                 const u32* __restrict__ startb,
                                                 u32* __restrict__ cursor,
                                                 u32* __restrict__ pts) {
  int n = blockIdx.x * 256 + threadIdx.x;
  int x = coords[n * 3], y = coords[n * 3 + 1], z = coords[n * 3 + 2];
  int c = x * 128 + y;
  u32 slot = atomicAdd(&cursor[c], 1u);
  pts[startb[c] + slot] = ((u32)z << 14) | (u32)n;  // z:7b | idx:14b
}

__global__ __launch_bounds__(256) void k_select(const int* __restrict__ coords,
                                                const u32* __restrict__ startb,
                                                const u32* __restrict__ cnt,
                                                const u32* __restrict__ pts,
                                                int* __restrict__ idxo) {
  int n = blockIdx.x * 256 + threadIdx.x;
  int x = coords[n * 3], y = coords[n * 3 + 1], z = coords[n * 3 + 2];
  u32 best[16];
#pragma unroll
  for (int j = 0; j < 16; j++) best[j] = 0xFFFFFFFFu;
  const int dxs[13] = {0, -1, 1, 0, 0, -2, 2, 0, 0, -1, -1, 1, 1};
  const int dys[13] = {0, 0, 0, -1, 1, 0, 0, -2, 2, -1, 1, -1, 1};
  const int dbs[13] = {0, 1, 1, 1, 1, 2, 2, 2, 2, 2, 2, 2, 2};
#pragma unroll
  for (int t = 0; t < 13; t++) {
    int xx = x + dxs[t], yy = y + dys[t];
    if (xx < 0 || xx > 127 || yy < 0 || yy > 127) continue;
    int c = xx * 128 + yy;
    u32 s0 = startb[c], e0 = s0 + cnt[c];
    for (u32 i = s0; i < e0; ++i) {
      u32 p = pts[i];
      int zq = (int)(p >> 14);
      int id = (int)(p & 16383u);
      int az = z - zq; az = az < 0 ? -az : az;
      int dd = dbs[t] + az;
      u32 key = (dd <= 2) ? (((u32)dd << 14) | (u32)id) : 0xFFFFFFFFu;
#pragma unroll
      for (int j = 0; j < 16; j++) {
        u32 lo = min(best[j], key);
        u32 hi = max(best[j], key);
        best[j] = lo; key = hi;
      }
    }
  }
#pragma unroll
  for (int j = 0; j < 16; j++)
    idxo[n * 16 + j] = (best[j] == 0xFFFFFFFFu) ? -1 : (int)(best[j] & 16383u);
}

// ---------------- weight cast+transpose: W (K x N fp32) -> WT (N x K bf16) ----------------
struct WSet { const float* s[6]; u16* d[6]; int K[6]; int N[6]; };

__global__ __launch_bounds__(256) void k_wcast(WSet ws) {
  int w = blockIdx.y;
  const float* S = ws.s[w]; u16* D = ws.d[w];
  int K = ws.K[w], N = ws.N[w];
  int ntx = N >> 5, tiles = ntx * (K >> 5);
  int t = blockIdx.x;
  if (t >= tiles) return;
  int n0 = (t % ntx) * 32, k0 = (t / ntx) * 32;
  __shared__ float st[32][33];
  int tr = threadIdx.x >> 3, tc4 = (threadIdx.x & 7) * 4;
  float4 v = *(const float4*)(S + (size_t)(k0 + tr) * N + n0 + tc4);
  st[tc4 + 0][tr] = v.x; st[tc4 + 1][tr] = v.y;
  st[tc4 + 2][tr] = v.z; st[tc4 + 3][tr] = v.w;
  __syncthreads();
  u16 o4[4];
  o4[0] = f2bf(st[tr][tc4 + 0]); o4[1] = f2bf(st[tr][tc4 + 1]);
  o4[2] = f2bf(st[tr][tc4 + 2]); o4[3] = f2bf(st[tr][tc4 + 3]);
  *(uint2*)(D + (size_t)(n0 + tr) * K + k0 + tc4) = *(uint2*)o4;
}

// ---------------- src = features@proj_w + proj_b + PE(coords) -> bf16 ----------------
__global__ __launch_bounds__(256) void k_src(const int* __restrict__ coords,
                                             const float* __restrict__ feats,
                                             const float* __restrict__ pw1,
                                             const float* __restrict__ pb1,
                                             const float* __restrict__ pw2,
                                             const float* __restrict__ pb2,
                                             const float* __restrict__ projw,
                                             const float* __restrict__ projb,
                                             u16* __restrict__ srcb) {
  __shared__ float sf[16][64];
  __shared__ float sh[16][128];
  int r0 = blockIdx.x * 16;
  int tid = threadIdx.x;
  {
    int e = tid * 4, r = e >> 6, c = e & 63;
    *(float4*)&sf[r][c] = *(const float4*)(feats + (r0 + r) * 64 + c);
  }
  {
    int j = tid & 127, half = tid >> 7;
#pragma unroll
    for (int rr = 0; rr < 8; rr++) {
      int r = half * 8 + rr;
      float x0 = (float)coords[(r0 + r) * 3 + 0] * (1.f / 127.f);
      float x1 = (float)coords[(r0 + r) * 3 + 1] * (1.f / 127.f);
      float x2 = (float)coords[(r0 + r) * 3 + 2] * (1.f / 127.f);
      float hv = pb1[j] + x0 * pw1[j] + x1 * pw1[128 + j] + x2 * pw1[256 + j];
      sh[r][j] = fmaxf(hv, 0.f);
    }
  }
  __syncthreads();
  int d = tid;
  float acc[16];
  float pb = projb[d] + pb2[d];
#pragma unroll
  for (int r = 0; r < 16; r++) acc[r] = pb;
  for (int c = 0; c < 64; c++) {
    float w = projw[c * 256 + d];
#pragma unroll
    for (int r = 0; r < 16; r++) acc[r] += sf[r][c] * w;
  }
  for (int j = 0; j < 128; j++) {
    float w = pw2[j * 256 + d];
#pragma unroll
    for (int r = 0; r < 16; r++) acc[r] += sh[r][j] * w;
  }
#pragma unroll
  for (int r = 0; r < 16; r++) srcb[(r0 + r) * 256 + d] = f2bf(acc[r]);
}

// ---------------- bf16 MFMA GEMM: C = A(MxK) @ WT(NxK)^T ----------------
// 128x128 tile, BK=32, 256 threads (4 waves in 2x2), 16x16x32 MFMA,
// global_load_lds width-16 staging (m97 structure).
template <int ACT, int SF32, int SBF16, int ADD>
__global__ __launch_bounds__(256) void k_mfma_gemm(
    const u16* __restrict__ A, const u16* __restrict__ WT,
    const float* __restrict__ bias,
    float* __restrict__ Cf, u16* __restrict__ Cb,
    const float* __restrict__ Addp,
    int M, int K, int N) {
  __shared__ __align__(16) u16 As[128 * 32];
  __shared__ __align__(16) u16 Bs[128 * 32];
  const int tid = threadIdx.x;
  const int wave = tid >> 6, lane = tid & 63;
  const int bm = blockIdx.y * 128, bn = blockIdx.x * 128;
  const int wr = (wave >> 1) * 64, wc = (wave & 1) * 64;

  f32x4 acc[4][4];
#pragma unroll
  for (int i = 0; i < 4; i++)
#pragma unroll
    for (int j = 0; j < 4; j++)
#pragma unroll
      for (int r = 0; r < 4; r++) acc[i][j][r] = 0.f;

  for (int k0 = 0; k0 < K; k0 += 32) {
#pragma unroll
    for (int i = 0; i < 2; i++) {
      int cb = i * 256 + wave * 64;         // wave-chunk base (uniform per wave)
      int c = cb + lane;                    // chunk id: 16B each
      int row = c >> 2, ko = (c & 3) * 8;
      __builtin_amdgcn_global_load_lds(
          (const __attribute__((address_space(1))) void*)(A + (size_t)(bm + row) * K + k0 + ko),
          (__attribute__((address_space(3))) void*)(As + (size_t)cb * 8), 16, 0, 0);
      __builtin_amdgcn_global_load_lds(
          (const __attribute__((address_space(1))) void*)(WT + (size_t)(bn + row) * K + k0 + ko),
          (__attribute__((address_space(3))) void*)(Bs + (size_t)cb * 8), 16, 0, 0);
    }
    __syncthreads();
    short8 af[4], bg[4];
#pragma unroll
    for (int i = 0; i < 4; i++)
      af[i] = *(const short8*)&As[(wr + i * 16 + (lane & 15)) * 32 + (lane >> 4) * 8];
#pragma unroll
    for (int j = 0; j < 4; j++)
      bg[j] = *(const short8*)&Bs[(wc + j * 16 + (lane & 15)) * 32 + (lane >> 4) * 8];
#pragma unroll
    for (int i = 0; i < 4; i++)
#pragma unroll
      for (int j = 0; j < 4; j++)
        acc[i][j] = __builtin_amdgcn_mfma_f32_16x16x32_bf16(af[i], bg[j], acc[i][j], 0, 0, 0);
    __syncthreads();
  }

#pragma unroll
  for (int j = 0; j < 4; j++) {
    int cc = bn + wc + j * 16 + (lane & 15);
    float bval = bias ? bias[cc] : 0.f;
#pragma unroll
    for (int i = 0; i < 4; i++) {
      int rbase = bm + wr + i * 16 + (lane >> 4) * 4;
#pragma unroll
      for (int r = 0; r < 4; r++) {
        float v = acc[i][j][r] + bval;
        size_t o = (size_t)(rbase + r) * N + cc;
        if (ADD) v += Addp[o];
        if (ACT) v = fmaxf(v, 0.f);
        if (SF32) Cf[o] = v;
        if (SBF16) Cb[o] = f2bf(v);
      }
    }
  }
}

// ---------------- fp32 tiled GEMM (kept for the N=64 tail GEMMs) ----------------
template <int ACT>
__global__ __launch_bounds__(256) void k_gemm(const float* __restrict__ A,
                                              const float* __restrict__ Wm,
                                              const float* __restrict__ bias,
                                              float* __restrict__ C,
                                              int M, int K, int Nn) {
  __shared__ float As[16][64];
  __shared__ float Bs[16][64];
  const int tid = threadIdx.x;
  const int bm = blockIdx.y * 64, bn = blockIdx.x * 64;
  const int tx = tid & 15, ty = tid >> 4;
  float acc[4][4];
#pragma unroll
  for (int i = 0; i < 4; i++)
#pragma unroll
    for (int j = 0; j < 4; j++) acc[i][j] = 0.f;
  const int ar = tid >> 2, ak = (tid & 3) * 4;
  const int wk_ = tid >> 4, wn = (tid & 15) * 4;
  for (int k0 = 0; k0 < K; k0 += 16) {
    float4 av = *(const float4*)(A + (bm + ar) * K + k0 + ak);
    As[ak + 0][ar] = av.x; As[ak + 1][ar] = av.y;
    As[ak + 2][ar] = av.z; As[ak + 3][ar] = av.w;
    float4 wv = *(const float4*)(Wm + (k0 + wk_) * Nn + bn + wn);
    *(float4*)&Bs[wk_][wn] = wv;
    __syncthreads();
#pragma unroll
    for (int k = 0; k < 16; k++) {
      float4 a = *(const float4*)&As[k][ty * 4];
      float4 b = *(const float4*)&Bs[k][tx * 4];
      acc[0][0] += a.x * b.x; acc[0][1] += a.x * b.y; acc[0][2] += a.x * b.z; acc[0][3] += a.x * b.w;
      acc[1][0] += a.y * b.x; acc[1][1] += a.y * b.y; acc[1][2] += a.y * b.z; acc[1][3] += a.y * b.w;
      acc[2][0] += a.z * b.x; acc[2][1] += a.z * b.y; acc[2][2] += a.z * b.z; acc[2][3] += a.z * b.w;
      acc[3][0] += a.w * b.x; acc[3][1] += a.w * b.y; acc[3][2] += a.w * b.z; acc[3][3] += a.w * b.w;
    }
    __syncthreads();
  }
  float4 bb = make_float4(0.f, 0.f, 0.f, 0.f);
  if (bias) bb = *(const float4*)(bias + bn + tx * 4);
#pragma unroll
  for (int i = 0; i < 4; i++) {
    int row = bm + ty * 4 + i;
    float4 o;
    o.x = acc[i][0] + bb.x; o.y = acc[i][1] + bb.y;
    o.z = acc[i][2] + bb.z; o.w = acc[i][3] + bb.w;
    if (ACT) {
      o.x = fmaxf(o.x, 0.f); o.y = fmaxf(o.y, 0.f);
      o.z = fmaxf(o.z, 0.f); o.w = fmaxf(o.w, 0.f);
    }
    *(float4*)(C + row * Nn + bn + tx * 4) = o;
  }
}

// ---------------- attention: one thread per (n, head), bf16 I/O ----------------
__global__ __launch_bounds__(256) void k_attn(const u16* __restrict__ Q,
                                              const u16* __restrict__ Kk,
                                              const u16* __restrict__ V,
                                              const int* __restrict__ idx,
                                              const float* __restrict__ bq,
                                              const float* __restrict__ bk,
                                              const float* __restrict__ bv,
                                              u16* __restrict__ outp) {
  int gid = blockIdx.x * 256 + threadIdx.x;
  int n = gid >> 3, h = gid & 7;
  const int* ip = idx + n * 16;
  const int hb = h * 32;
  float q[32];
  {
    int i0 = ip[0];  // slot0: nearest (dist 0) — always valid
    const u16* qp = Q + (size_t)i0 * 256 + hb;
#pragma unroll
    for (int j = 0; j < 32; j += 8) ldbf8(qp + j, &q[j]);
#pragma unroll
    for (int j = 0; j < 32; j++) q[j] += bq[hb + j];
  }
  float qbk = 0.f;
#pragma unroll
  for (int j = 0; j < 32; j++) qbk += q[j] * bk[hb + j];
  float s[16]; int ii[16];
#pragma unroll
  for (int m = 0; m < 16; m++) {
    int i = ip[m]; ii[m] = i;
    float d = qbk;
    if (i >= 0) {
      const u16* kp = Kk + (size_t)i * 256 + hb;
      float kv[32];
#pragma unroll
      for (int j = 0; j < 32; j += 8) ldbf8(kp + j, &kv[j]);
#pragma unroll
      for (int j = 0; j < 32; j++) d += q[j] * kv[j];
    }
    s[m] = d * 0.17677669529663689f;  // 1/sqrt(32)
  }
  float mx = s[0];
#pragma unroll
  for (int m = 1; m < 16; m++) mx = fmaxf(mx, s[m]);
  float sum = 0.f;
#pragma unroll
  for (int m = 0; m < 16; m++) { s[m] = __expf(s[m] - mx); sum += s[m]; }
  float inv = 1.f / sum;
  float o[32];
#pragma unroll
  for (int j = 0; j < 32; j++) o[j] = 0.f;
#pragma unroll
  for (int m = 0; m < 16; m++) {
    if (ii[m] >= 0) {
      const u16* vp = V + (size_t)ii[m] * 256 + hb;
      float vv[32];
#pragma unroll
      for (int j = 0; j < 32; j += 8) ldbf8(vp + j, &vv[j]);
#pragma unroll
      for (int j = 0; j < 32; j++) o[j] += s[m] * vv[j];
    }
  }
  u16* op = outp + (size_t)n * 256 + hb;
#pragma unroll
  for (int j = 0; j < 32; j += 8) {
    u16 tmp[8];
#pragma unroll
    for (int jj = 0; jj < 8; jj++) tmp[jj] = f2bf(o[j + jj] * inv + bv[hb + j + jj]);
    *(uint4*)(op + j) = *(uint4*)tmp;
  }
}

// ---------------- layernorm over D=256 of x, one wave per row ----------------
__global__ __launch_bounds__(256) void k_ln(const float* __restrict__ xx,
                                            const float* __restrict__ g,
                                            const float* __restrict__ b,
                                            float* __restrict__ y) {
  int row = blockIdx.x * 4 + (threadIdx.x >> 6);
  int lane = threadIdx.x & 63;
  float4 a = *(const float4*)(xx + (size_t)row * 256 + lane * 4);
  float x0 = a.x, x1 = a.y, x2 = a.z, x3 = a.w;
  float sm = x0 + x1 + x2 + x3;
#pragma unroll
  for (int off = 1; off < 64; off <<= 1) sm += __shfl_xor(sm, off);
  float mu = sm * (1.f / 256.f);
  float d0 = x0 - mu, d1 = x1 - mu, d2 = x2 - mu, d3 = x3 - mu;
  float sq = d0 * d0 + d1 * d1 + d2 * d2 + d3 * d3;
#pragma unroll
  for (int off = 1; off < 64; off <<= 1) sq += __shfl_xor(sq, off);
  float rstd = rsqrtf(sq * (1.f / 256.f) + kEPS);
  float4 gv = *(const float4*)(g + lane * 4);
  float4 bv4 = *(const float4*)(b + lane * 4);
  float4 o;
  o.x = d0 * rstd * gv.x + bv4.x; o.y = d1 * rstd * gv.y + bv4.y;
  o.z = d2 * rstd * gv.z + bv4.z; o.w = d3 * rstd * gv.w + bv4.w;
  *(float4*)(y + (size_t)row * 256 + lane * 4) = o;
}

// ---------------- concat [features | t] -> (N,128) ----------------
__global__ __launch_bounds__(256) void k_cat(const float* __restrict__ feats,
                                             const float* __restrict__ t,
                                             float* __restrict__ cat) {
  int gid = blockIdx.x * 256 + threadIdx.x;
  int e = gid * 4, n = e >> 7, c = e & 127;
  float4 v = (c < 64) ? *(const float4*)(feats + n * 64 + c)
                      : *(const float4*)(t + n * 64 + (c - 64));
  *(float4*)(cat + e) = v;
}

// ---------------- batchnorm ----------------
__global__ __launch_bounds__(256) void k_stats(const float* __restrict__ f,
                                               float* __restrict__ pS, float* __restrict__ pQ) {
  int col = threadIdx.x & 63, rc = threadIdx.x >> 6;
  int r0 = blockIdx.x * 128 + rc * 32;
  float s = 0.f, q = 0.f;
  for (int r = 0; r < 32; r++) {
    float v = f[(size_t)(r0 + r) * 64 + col];
    s += v; q += v * v;
  }
  __shared__ float ls[4][64], lq[4][64];
  ls[rc][col] = s; lq[rc][col] = q;
  __syncthreads();
  if (rc == 0) {
    s = ls[0][col] + ls[1][col] + ls[2][col] + ls[3][col];
    q = lq[0][col] + lq[1][col] + lq[2][col] + lq[3][col];
    pS[blockIdx.x * 64 + col] = s;
    pQ[blockIdx.x * 64 + col] = q;
  }
}

__global__ __launch_bounds__(64) void k_bnfin(const float* __restrict__ pS,
                                              const float* __restrict__ pQ,
                                              const float* __restrict__ g,
                                              const float* __restrict__ b,
                                              float* __restrict__ coef,
                                              float* __restrict__ shift) {
  int c = threadIdx.x;
  float s = 0.f, q = 0.f;
  for (int i = 0; i < 128; i++) { s += pS[i * 64 + c]; q += pQ[i * 64 + c]; }
  float mu = s * (1.f / 16384.f);
  float var = q * (1.f / 16384.f) - mu * mu;
  float cf = rsqrtf(var + kEPS) * g[c];
  coef[c] = cf;
  shift[c] = b[c] - mu * cf;
}

__global__ __launch_bounds__(256) void k_bnapply(const float* __restrict__ f,
                                                 const float* __restrict__ coef,
                                                 const float* __restrict__ shift,
                                                 float* __restrict__ out) {
  int gid = blockIdx.x * 256 + threadIdx.x;
  int e = gid * 4, col = e & 63;
  float4 v = *(const float4*)(f + e);
  float4 cf = *(const float4*)(coef + col);
  float4 sh = *(const float4*)(shift + col);
  float4 o;
  o.x = fmaxf(v.x * cf.x + sh.x, 0.f);
  o.y = fmaxf(v.y * cf.y + sh.y, 0.f);
  o.z = fmaxf(v.z * cf.z + sh.z, 0.f);
  o.w = fmaxf(v.w * cf.w + sh.w, 0.f);
  *(float4*)(out + e) = o;
}

// ---------------- launch ----------------
extern "C" void kernel_launch(void* const* d_in, const int* in_sizes, int n_in,
                              void* d_out, int out_size, void* d_ws, size_t ws_size,
                              hipStream_t stream) {
  (void)in_sizes; (void)n_in; (void)out_size; (void)ws_size;
  const int*   coords = (const int*)d_in[0];
  const float* feats  = (const float*)d_in[1];
  const float* pe_w1  = (const float*)d_in[2];
  const float* pe_b1  = (const float*)d_in[3];
  const float* pe_w2  = (const float*)d_in[4];
  const float* pe_b2  = (const float*)d_in[5];
  const float* proj_w = (const float*)d_in[6];
  const float* proj_b = (const float*)d_in[7];
  const float* wq  = (const float*)d_in[8];
  const float* bq  = (const float*)d_in[9];
  const float* wk  = (const float*)d_in[10];
  const float* bk  = (const float*)d_in[11];
  const float* wv  = (const float*)d_in[12];
  const float* bv  = (const float*)d_in[13];
  const float* wo  = (const float*)d_in[14];
  const float* bo  = (const float*)d_in[15];
  const float* fw1 = (const float*)d_in[16];
  const float* fb1 = (const float*)d_in[17];
  const float* fw2 = (const float*)d_in[18];
  const float* fb2 = (const float*)d_in[19];
  const float* lng = (const float*)d_in[20];
  const float* lnb = (const float*)d_in[21];
  const float* uw1 = (const float*)d_in[22];
  const float* ub1 = (const float*)d_in[23];
  const float* uw2 = (const float*)d_in[24];
  const float* ub2 = (const float*)d_in[25];
  const float* bng = (const float*)d_in[26];
  const float* bnb = (const float*)d_in[27];
  float* out = (float*)d_out;

  char* Wc = (char*)d_ws;
  const size_t MB = 1u << 20;
  // live ranges (see journal): regions reused once the producer phase ends.
  u16*   Qb    = (u16*)(Wc + 0 * MB);        // 8MB; dead after attn
  u16*   Kb    = (u16*)(Wc + 8 * MB);        // 8MB; dead after attn
  u16*   Vb    = (u16*)(Wc + 16 * MB);       // 8MB; dead after attn
  u16*   srcb  = (u16*)(Wc + 24 * MB);       // 8MB; dead after QKV
  u16*   aoInB = srcb;                       // attn out (bf16); dead after wo
  float* tB    = (float*)(Wc + 24 * MB);     // 4MB (after wo)
  float* fB    = (float*)(Wc + 28 * MB);     // 4MB
  float* aoF   = (float*)(Wc + 32 * MB);     // 16MB; read by ffn2 epilogue
  u16*   aoB   = (u16*)(Wc + 48 * MB);       // 8MB; dead after ffn1
  u16*   h1B   = (u16*)(Wc + 56 * MB);       // 16MB; dead after ffn2
  float* xB    = (float*)(Wc + 72 * MB);     // 16MB; dead after LN
  float* catB  = (float*)(Wc + 72 * MB);     // 8MB (after LN)
  float* yB    = (float*)(Wc + 0 * MB);      // 16MB (after attn; over Qb+Kb)

  u16* wqT  = (u16*)(Wc + 88 * MB);          // 256x256
  u16* wkT  = wqT + 65536;
  u16* wvT  = wkT + 65536;
  u16* woT  = wvT + 65536;
  u16* fw1T = woT + 65536;                   // 512x256
  u16* fw2T = fw1T + 131072;                 // 256x512

  u32* cnt    = (u32*)(Wc + 89 * MB);
  u32* cursor = cnt + 16384;
  u32* startb = cnt + 32768;
  u32* pts    = cnt + 49152;
  int* idxb   = (int*)(cnt + 65536);         // N*16
  float* pS    = (float*)(cnt + 65536 + 262144);
  float* pQ    = pS + 8192;
  float* coefb = pQ + 8192;
  float* shb   = coefb + 64;

  hipMemsetAsync(cnt, 0, 32768 * sizeof(u32), stream);  // cnt + cursor

  k_hist<<<64, 256, 0, stream>>>(coords, cnt);
  k_scan<<<1, 256, 0, stream>>>(cnt, startb);
  k_scatter<<<64, 256, 0, stream>>>(coords, startb, cursor, pts);
  k_select<<<64, 256, 0, stream>>>(coords, startb, cnt, pts, idxb);

  WSet wset;
  wset.s[0] = wq;  wset.d[0] = wqT;  wset.K[0] = 256; wset.N[0] = 256;
  wset.s[1] = wk;  wset.d[1] = wkT;  wset.K[1] = 256; wset.N[1] = 256;
  wset.s[2] = wv;  wset.d[2] = wvT;  wset.K[2] = 256; wset.N[2] = 256;
  wset.s[3] = wo;  wset.d[3] = woT;  wset.K[3] = 256; wset.N[3] = 256;
  wset.s[4] = fw1; wset.d[4] = fw1T; wset.K[4] = 256; wset.N[4] = 512;
  wset.s[5] = fw2; wset.d[5] = fw2T; wset.K[5] = 512; wset.N[5] = 256;
  k_wcast<<<dim3(128, 6), 256, 0, stream>>>(wset);

  k_src<<<1024, 256, 0, stream>>>(coords, feats, pe_w1, pe_b1, pe_w2, pe_b2,
                                  proj_w, proj_b, srcb);

  k_mfma_gemm<0, 0, 1, 0><<<dim3(2, 128), 256, 0, stream>>>(srcb, wqT, nullptr, nullptr, Qb, nullptr, kN, 256, 256);
  k_mfma_gemm<0, 0, 1, 0><<<dim3(2, 128), 256, 0, stream>>>(srcb, wkT, nullptr, nullptr, Kb, nullptr, kN, 256, 256);
  k_mfma_gemm<0, 0, 1, 0><<<dim3(2, 128), 256, 0, stream>>>(srcb, wvT, nullptr, nullptr, Vb, nullptr, kN, 256, 256);

  k_attn<<<512, 256, 0, stream>>>(Qb, Kb, Vb, idxb, bq, bk, bv, aoInB);

  // ao = attn_out @ wo + bo  (fp32 for residual, bf16 for ffn1)
  k_mfma_gemm<0, 1, 1, 0><<<dim3(2, 128), 256, 0, stream>>>(aoInB, woT, bo, aoF, aoB, nullptr, kN, 256, 256);
  // h1 = relu(ao @ fw1 + fb1) (bf16)
  k_mfma_gemm<1, 0, 1, 0><<<dim3(4, 128), 256, 0, stream>>>(aoB, fw1T, fb1, nullptr, h1B, nullptr, kN, 256, 512);
  // x = ao + (h1 @ fw2 + fb2) (fp32, residual fused)
  k_mfma_gemm<0, 1, 0, 1><<<dim3(2, 128), 256, 0, stream>>>(h1B, fw2T, fb2, xB, nullptr, aoF, kN, 512, 256);

  k_ln<<<4096, 256, 0, stream>>>(xB, lng, lnb, yB);

  k_gemm<0><<<dim3(1, 256), 256, 0, stream>>>(yB, uw1, ub1, tB, kN, 256, 64);
  k_cat<<<2048, 256, 0, stream>>>(feats, tB, catB);
  k_gemm<0><<<dim3(1, 256), 256, 0, stream>>>(catB, uw2, ub2, fB, kN, 128, 64);

  k_stats<<<128, 256, 0, stream>>>(fB, pS, pQ);
  k_bnfin<<<1, 64, 0, stream>>>(pS, pQ, bng, bnb, coefb, shb);
  k_bnapply<<<1024, 256, 0, stream>>>(fB, coefb, shb, out);
}

// Round 3
// 276.538 us; speedup vs baseline: 1.8222x; 1.1457x over previous
//
#include <hip/hip_runtime.h>
#include <stdint.h>

typedef unsigned short u16;
typedef unsigned int   u32;
typedef __attribute__((ext_vector_type(8))) short short8;
typedef __attribute__((ext_vector_type(4))) float f32x4;

static constexpr int kN = 16384;
static constexpr float kEPS = 1e-5f;

__device__ __forceinline__ u16 f2bf(float x) {
  u32 u = __float_as_uint(x);
  u32 r = (u + 0x7fffu + ((u >> 16) & 1u)) >> 16;
  return (u16)r;
}
__device__ __forceinline__ void ldbf8(const u16* p, float* o) {
  uint4 v = *(const uint4*)p;
  o[0] = __uint_as_float(v.x << 16);  o[1] = __uint_as_float(v.x & 0xffff0000u);
  o[2] = __uint_as_float(v.y << 16);  o[3] = __uint_as_float(v.y & 0xffff0000u);
  o[4] = __uint_as_float(v.z << 16);  o[5] = __uint_as_float(v.z & 0xffff0000u);
  o[6] = __uint_as_float(v.w << 16);  o[7] = __uint_as_float(v.w & 0xffff0000u);
}

// ---------------- neighbor grid (cells = x*128+y) ----------------

__global__ __launch_bounds__(256) void k_hist(const int* __restrict__ coords,
                                              u32* __restrict__ cnt) {
  int n = blockIdx.x * 256 + threadIdx.x;
  int c = coords[n * 3] * 128 + coords[n * 3 + 1];
  atomicAdd(&cnt[c], 1u);
}

__global__ __launch_bounds__(256) void k_scan(const u32* __restrict__ cnt,
                                              u32* __restrict__ startb) {
  __shared__ u32 tots[256];
  int t = threadIdx.x;
  int base = t * 64;
  u32 s = 0;
  for (int i = 0; i < 64; i++) s += cnt[base + i];
  tots[t] = s;
  __syncthreads();
  if (t == 0) {
    u32 run = 0;
    for (int i = 0; i < 256; i++) { u32 v = tots[i]; tots[i] = run; run += v; }
  }
  __syncthreads();
  u32 run = tots[t];
  for (int i = 0; i < 64; i++) { startb[base + i] = run; run += cnt[base + i]; }
}

__global__ __launch_bounds__(256) void k_scatter(const int* __restrict__ coords,
                                                 const u32* __restrict__ startb,
                                                 u32* __restrict__ cursor,
                                                 u32* __restrict__ pts) {
  int n = blockIdx.x * 256 + threadIdx.x;
  int x = coords[n * 3], y = coords[n * 3 + 1], z = coords[n * 3 + 2];
  int c = x * 128 + y;
  u32 slot = atomicAdd(&cursor[c], 1u);
  pts[startb[c] + slot] = ((u32)z << 14) | (u32)n;  // z:7b | idx:14b
}

__global__ __launch_bounds__(256) void k_select(const int* __restrict__ coords,
                                                const u32* __restrict__ startb,
                                                const u32* __restrict__ cnt,
                                                const u32* __restrict__ pts,
                                                int* __restrict__ idxo) {
  int n = blockIdx.x * 256 + threadIdx.x;
  int x = coords[n * 3], y = coords[n * 3 + 1], z = coords[n * 3 + 2];
  u32 best[16];
#pragma unroll
  for (int j = 0; j < 16; j++) best[j] = 0xFFFFFFFFu;
  const int dxs[13] = {0, -1, 1, 0, 0, -2, 2, 0, 0, -1, -1, 1, 1};
  const int dys[13] = {0, 0, 0, -1, 1, 0, 0, -2, 2, -1, 1, -1, 1};
  const int dbs[13] = {0, 1, 1, 1, 1, 2, 2, 2, 2, 2, 2, 2, 2};
#pragma unroll
  for (int t = 0; t < 13; t++) {
    int xx = x + dxs[t], yy = y + dys[t];
    if (xx < 0 || xx > 127 || yy < 0 || yy > 127) continue;
    int c = xx * 128 + yy;
    u32 s0 = startb[c], e0 = s0 + cnt[c];
    for (u32 i = s0; i < e0; ++i) {
      u32 p = pts[i];
      int zq = (int)(p >> 14);
      int id = (int)(p & 16383u);
      int az = z - zq; az = az < 0 ? -az : az;
      int dd = dbs[t] + az;
      u32 key = (dd <= 2) ? (((u32)dd << 14) | (u32)id) : 0xFFFFFFFFu;
#pragma unroll
      for (int j = 0; j < 16; j++) {
        u32 lo = min(best[j], key);
        u32 hi = max(best[j], key);
        best[j] = lo; key = hi;
      }
    }
  }
#pragma unroll
  for (int j = 0; j < 16; j++)
    idxo[n * 16 + j] = (best[j] == 0xFFFFFFFFu) ? -1 : (int)(best[j] & 16383u);
}

// ------- weight cast+transpose: S (K x N fp32), dest row n gets col k:
//         D[n*dstride + coff + k] = bf16(S[k*N + n]) -------
struct WSet {
  const float* s[10]; u16* d[10];
  int K[10]; int N[10]; int dstride[10]; int coff[10];
};

__global__ __launch_bounds__(256) void k_wcast(WSet ws) {
  int w = blockIdx.y;
  const float* S = ws.s[w]; u16* D = ws.d[w];
  int K = ws.K[w], N = ws.N[w], ds = ws.dstride[w], co = ws.coff[w];
  int ntx = N >> 5, tiles = ntx * (K >> 5);
  int t = blockIdx.x;
  if (t >= tiles) return;
  int n0 = (t % ntx) * 32, k0 = (t / ntx) * 32;
  __shared__ float st[32][33];
  int tr = threadIdx.x >> 3, tc4 = (threadIdx.x & 7) * 4;
  float4 v = *(const float4*)(S + (size_t)(k0 + tr) * N + n0 + tc4);
  st[tc4 + 0][tr] = v.x; st[tc4 + 1][tr] = v.y;
  st[tc4 + 2][tr] = v.z; st[tc4 + 3][tr] = v.w;
  __syncthreads();
  u16 o4[4];
  o4[0] = f2bf(st[tr][tc4 + 0]); o4[1] = f2bf(st[tr][tc4 + 1]);
  o4[2] = f2bf(st[tr][tc4 + 2]); o4[3] = f2bf(st[tr][tc4 + 3]);
  *(uint2*)(D + (size_t)(n0 + tr) * ds + co + k0 + tc4) = *(uint2*)o4;
}

// pbc = proj_b + pe_b2
__global__ __launch_bounds__(256) void k_bias2(const float* __restrict__ a,
                                               const float* __restrict__ b,
                                               float* __restrict__ o) {
  int t = threadIdx.x;
  o[t] = a[t] + b[t];
}

// ---------------- A1 = [features | relu(PE hidden)] bf16, N x 192 ----------------
__global__ __launch_bounds__(256) void k_prep(const int* __restrict__ coords,
                                              const float* __restrict__ feats,
                                              const float* __restrict__ pw1,
                                              const float* __restrict__ pb1,
                                              u16* __restrict__ A1) {
  int r0 = blockIdx.x * 32;
#pragma unroll
  for (int s = 0; s < 3; s++) {
    int j = threadIdx.x + s * 256;  // 0..767 = 32 rows x 24 segs
    int row = j / 24, seg = j % 24;
    int n = r0 + row;
    u16 o[8];
    if (seg < 8) {
      const float* fp = feats + (size_t)n * 64 + seg * 8;
      float4 a = *(const float4*)fp;
      float4 b = *(const float4*)(fp + 4);
      o[0] = f2bf(a.x); o[1] = f2bf(a.y); o[2] = f2bf(a.z); o[3] = f2bf(a.w);
      o[4] = f2bf(b.x); o[5] = f2bf(b.y); o[6] = f2bf(b.z); o[7] = f2bf(b.w);
    } else {
      int jj0 = (seg - 8) * 8;
      float x0 = (float)coords[n * 3 + 0] * (1.f / 127.f);
      float x1 = (float)coords[n * 3 + 1] * (1.f / 127.f);
      float x2 = (float)coords[n * 3 + 2] * (1.f / 127.f);
#pragma unroll
      for (int u = 0; u < 8; u++) {
        int jj = jj0 + u;
        float hv = pb1[jj] + x0 * pw1[jj] + x1 * pw1[128 + jj] + x2 * pw1[256 + jj];
        o[u] = f2bf(fmaxf(hv, 0.f));
      }
    }
    *(uint4*)(A1 + (size_t)n * 192 + seg * 8) = *(uint4*)o;
  }
}

// ---------------- bf16 MFMA GEMM: C = A(MxK) @ WT(NxK)^T ----------------
// 128x128 tile, BK=32, 256 threads (4 waves 2x2), 16x16x32 MFMA, m97 staging.
// Handles N not multiple of 128 via B-row clamp + store guard.
template <int ACT, int SF32, int SBF16, int ADD>
__global__ __launch_bounds__(256) void k_mfma_gemm(
    const u16* __restrict__ A, const u16* __restrict__ WT,
    const float* __restrict__ bias,
    float* __restrict__ Cf, u16* __restrict__ Cb,
    const float* __restrict__ Addp,
    int M, int K, int N) {
  __shared__ __align__(16) u16 As[128 * 32];
  __shared__ __align__(16) u16 Bs[128 * 32];
  const int tid = threadIdx.x;
  const int wave = tid >> 6, lane = tid & 63;
  const int bm = blockIdx.y * 128, bn = blockIdx.x * 128;
  const int wr = (wave >> 1) * 64, wc = (wave & 1) * 64;

  f32x4 acc[4][4];
#pragma unroll
  for (int i = 0; i < 4; i++)
#pragma unroll
    for (int j = 0; j < 4; j++)
#pragma unroll
      for (int r = 0; r < 4; r++) acc[i][j][r] = 0.f;

  for (int k0 = 0; k0 < K; k0 += 32) {
#pragma unroll
    for (int i = 0; i < 2; i++) {
      int cb = i * 256 + wave * 64;   // wave-uniform chunk base (16B chunks)
      int c = cb + lane;
      int row = c >> 2, ko = (c & 3) * 8;
      int rowb = min(row, N - 1 - bn);  // clamp B row for N<tile
      __builtin_amdgcn_global_load_lds(
          (const __attribute__((address_space(1))) void*)(A + (size_t)(bm + row) * K + k0 + ko),
          (__attribute__((address_space(3))) void*)(As + (size_t)cb * 8), 16, 0, 0);
      __builtin_amdgcn_global_load_lds(
          (const __attribute__((address_space(1))) void*)(WT + (size_t)(bn + rowb) * K + k0 + ko),
          (__attribute__((address_space(3))) void*)(Bs + (size_t)cb * 8), 16, 0, 0);
    }
    __syncthreads();
    short8 af[4], bg[4];
#pragma unroll
    for (int i = 0; i < 4; i++)
      af[i] = *(const short8*)&As[(wr + i * 16 + (lane & 15)) * 32 + (lane >> 4) * 8];
#pragma unroll
    for (int j = 0; j < 4; j++)
      bg[j] = *(const short8*)&Bs[(wc + j * 16 + (lane & 15)) * 32 + (lane >> 4) * 8];
#pragma unroll
    for (int i = 0; i < 4; i++)
#pragma unroll
      for (int j = 0; j < 4; j++)
        acc[i][j] = __builtin_amdgcn_mfma_f32_16x16x32_bf16(af[i], bg[j], acc[i][j], 0, 0, 0);
    __syncthreads();
  }

#pragma unroll
  for (int j = 0; j < 4; j++) {
    int cc = bn + wc + j * 16 + (lane & 15);
    if (cc >= N) continue;
    float bval = bias ? bias[cc] : 0.f;
#pragma unroll
    for (int i = 0; i < 4; i++) {
      int rbase = bm + wr + i * 16 + (lane >> 4) * 4;
#pragma unroll
      for (int r = 0; r < 4; r++) {
        float v = acc[i][j][r] + bval;
        size_t o = (size_t)(rbase + r) * N + cc;
        if (ADD) v += Addp[o];
        if (ACT) v = fmaxf(v, 0.f);
        if (SF32) Cf[o] = v;
        if (SBF16) Cb[o] = f2bf(v);
      }
    }
  }
}

// ---------------- attention: one thread per (n, head), fused QKV bf16 ----------------
// QKV row i: [0,256)=Q, [256,512)=K, [512,768)=V
__global__ __launch_bounds__(256) void k_attn(const u16* __restrict__ QKV,
                                              const int* __restrict__ idx,
                                              const float* __restrict__ bq,
                                              const float* __restrict__ bk,
                                              const float* __restrict__ bv,
                                              u16* __restrict__ outp) {
  int gid = blockIdx.x * 256 + threadIdx.x;
  int n = gid >> 3, h = gid & 7;
  const int* ip = idx + n * 16;
  const int hb = h * 32;
  float q[32];
  {
    int i0 = ip[0];  // slot0: dist 0 (self) — always valid
    const u16* qp = QKV + (size_t)i0 * 768 + hb;
#pragma unroll
    for (int j = 0; j < 32; j += 8) ldbf8(qp + j, &q[j]);
#pragma unroll
    for (int j = 0; j < 32; j++) q[j] += bq[hb + j];
  }
  float qbk = 0.f;
#pragma unroll
  for (int j = 0; j < 32; j++) qbk += q[j] * bk[hb + j];
  float s[16]; int ii[16];
#pragma unroll
  for (int m = 0; m < 16; m++) {
    int i = ip[m]; ii[m] = i;
    float d = qbk;
    if (i >= 0) {
      const u16* kp = QKV + (size_t)i * 768 + 256 + hb;
      float kv[32];
#pragma unroll
      for (int j = 0; j < 32; j += 8) ldbf8(kp + j, &kv[j]);
#pragma unroll
      for (int j = 0; j < 32; j++) d += q[j] * kv[j];
    }
    s[m] = d * 0.17677669529663689f;  // 1/sqrt(32)
  }
  float mx = s[0];
#pragma unroll
  for (int m = 1; m < 16; m++) mx = fmaxf(mx, s[m]);
  float sum = 0.f;
#pragma unroll
  for (int m = 0; m < 16; m++) { s[m] = __expf(s[m] - mx); sum += s[m]; }
  float inv = 1.f / sum;
  float o[32];
#pragma unroll
  for (int j = 0; j < 32; j++) o[j] = 0.f;
#pragma unroll
  for (int m = 0; m < 16; m++) {
    if (ii[m] >= 0) {
      const u16* vp = QKV + (size_t)ii[m] * 768 + 512 + hb;
      float vv[32];
#pragma unroll
      for (int j = 0; j < 32; j += 8) ldbf8(vp + j, &vv[j]);
#pragma unroll
      for (int j = 0; j < 32; j++) o[j] += s[m] * vv[j];
    }
  }
  u16* op = outp + (size_t)n * 256 + hb;
#pragma unroll
  for (int j = 0; j < 32; j += 8) {
    u16 tmp[8];
#pragma unroll
    for (int jj = 0; jj < 8; jj++) tmp[jj] = f2bf(o[j + jj] * inv + bv[hb + j + jj]);
    *(uint4*)(op + j) = *(uint4*)tmp;
  }
}

// ---------------- layernorm over D=256, one wave per row, bf16 out ----------------
__global__ __launch_bounds__(256) void k_ln(const float* __restrict__ xx,
                                            const float* __restrict__ g,
                                            const float* __restrict__ b,
                                            u16* __restrict__ y) {
  int row = blockIdx.x * 4 + (threadIdx.x >> 6);
  int lane = threadIdx.x & 63;
  float4 a = *(const float4*)(xx + (size_t)row * 256 + lane * 4);
  float x0 = a.x, x1 = a.y, x2 = a.z, x3 = a.w;
  float sm = x0 + x1 + x2 + x3;
#pragma unroll
  for (int off = 1; off < 64; off <<= 1) sm += __shfl_xor(sm, off);
  float mu = sm * (1.f / 256.f);
  float d0 = x0 - mu, d1 = x1 - mu, d2 = x2 - mu, d3 = x3 - mu;
  float sq = d0 * d0 + d1 * d1 + d2 * d2 + d3 * d3;
#pragma unroll
  for (int off = 1; off < 64; off <<= 1) sq += __shfl_xor(sq, off);
  float rstd = rsqrtf(sq * (1.f / 256.f) + kEPS);
  float4 gv = *(const float4*)(g + lane * 4);
  float4 bv4 = *(const float4*)(b + lane * 4);
  u16 o[4];
  o[0] = f2bf(d0 * rstd * gv.x + bv4.x); o[1] = f2bf(d1 * rstd * gv.y + bv4.y);
  o[2] = f2bf(d2 * rstd * gv.z + bv4.z); o[3] = f2bf(d3 * rstd * gv.w + bv4.w);
  *(uint2*)(y + (size_t)row * 256 + lane * 4) = *(uint2*)o;
}

// ---------------- concat [features | t] -> (N,128) bf16 ----------------
__global__ __launch_bounds__(256) void k_cat(const float* __restrict__ feats,
                                             const u16* __restrict__ t,
                                             u16* __restrict__ cat) {
  int gid = blockIdx.x * 256 + threadIdx.x;
  int e = gid * 8, n = e >> 7, c = e & 127;
  u16 o[8];
  if (c < 64) {
    const float* fp = feats + (size_t)n * 64 + c;
    float4 a = *(const float4*)fp;
    float4 b = *(const float4*)(fp + 4);
    o[0] = f2bf(a.x); o[1] = f2bf(a.y); o[2] = f2bf(a.z); o[3] = f2bf(a.w);
    o[4] = f2bf(b.x); o[5] = f2bf(b.y); o[6] = f2bf(b.z); o[7] = f2bf(b.w);
    *(uint4*)(cat + e) = *(uint4*)o;
  } else {
    *(uint4*)(cat + e) = *(const uint4*)(t + (size_t)n * 64 + (c - 64));
  }
}

// ---------------- batchnorm ----------------
__global__ __launch_bounds__(256) void k_stats(const float* __restrict__ f,
                                               float* __restrict__ pS, float* __restrict__ pQ) {
  int col = threadIdx.x & 63, rc = threadIdx.x >> 6;
  int r0 = blockIdx.x * 128 + rc * 32;
  float s = 0.f, q = 0.f;
  for (int r = 0; r < 32; r++) {
    float v = f[(size_t)(r0 + r) * 64 + col];
    s += v; q += v * v;
  }
  __shared__ float ls[4][64], lq[4][64];
  ls[rc][col] = s; lq[rc][col] = q;
  __syncthreads();
  if (rc == 0) {
    s = ls[0][col] + ls[1][col] + ls[2][col] + ls[3][col];
    q = lq[0][col] + lq[1][col] + lq[2][col] + lq[3][col];
    pS[blockIdx.x * 64 + col] = s;
    pQ[blockIdx.x * 64 + col] = q;
  }
}

__global__ __launch_bounds__(64) void k_bnfin(const float* __restrict__ pS,
                                              const float* __restrict__ pQ,
                                              const float* __restrict__ g,
                                              const float* __restrict__ b,
                                              float* __restrict__ coef,
                                              float* __restrict__ shift) {
  int c = threadIdx.x;
  float s = 0.f, q = 0.f;
  for (int i = 0; i < 128; i++) { s += pS[i * 64 + c]; q += pQ[i * 64 + c]; }
  float mu = s * (1.f / 16384.f);
  float var = q * (1.f / 16384.f) - mu * mu;
  float cf = rsqrtf(var + kEPS) * g[c];
  coef[c] = cf;
  shift[c] = b[c] - mu * cf;
}

__global__ __launch_bounds__(256) void k_bnapply(const float* __restrict__ f,
                                                 const float* __restrict__ coef,
                                                 const float* __restrict__ shift,
                                                 float* __restrict__ out) {
  int gid = blockIdx.x * 256 + threadIdx.x;
  int e = gid * 4, col = e & 63;
  float4 v = *(const float4*)(f + e);
  float4 cf = *(const float4*)(coef + col);
  float4 sh = *(const float4*)(shift + col);
  float4 o;
  o.x = fmaxf(v.x * cf.x + sh.x, 0.f);
  o.y = fmaxf(v.y * cf.y + sh.y, 0.f);
  o.z = fmaxf(v.z * cf.z + sh.z, 0.f);
  o.w = fmaxf(v.w * cf.w + sh.w, 0.f);
  *(float4*)(out + e) = o;
}

// ---------------- launch ----------------
extern "C" void kernel_launch(void* const* d_in, const int* in_sizes, int n_in,
                              void* d_out, int out_size, void* d_ws, size_t ws_size,
                              hipStream_t stream) {
  (void)in_sizes; (void)n_in; (void)out_size; (void)ws_size;
  const int*   coords = (const int*)d_in[0];
  const float* feats  = (const float*)d_in[1];
  const float* pe_w1  = (const float*)d_in[2];
  const float* pe_b1  = (const float*)d_in[3];
  const float* pe_w2  = (const float*)d_in[4];
  const float* pe_b2  = (const float*)d_in[5];
  const float* proj_w = (const float*)d_in[6];
  const float* proj_b = (const float*)d_in[7];
  const float* wq  = (const float*)d_in[8];
  const float* bq  = (const float*)d_in[9];
  const float* wk  = (const float*)d_in[10];
  const float* bk  = (const float*)d_in[11];
  const float* wv  = (const float*)d_in[12];
  const float* bv  = (const float*)d_in[13];
  const float* wo  = (const float*)d_in[14];
  const float* bo  = (const float*)d_in[15];
  const float* fw1 = (const float*)d_in[16];
  const float* fb1 = (const float*)d_in[17];
  const float* fw2 = (const float*)d_in[18];
  const float* fb2 = (const float*)d_in[19];
  const float* lng = (const float*)d_in[20];
  const float* lnb = (const float*)d_in[21];
  const float* uw1 = (const float*)d_in[22];
  const float* ub1 = (const float*)d_in[23];
  const float* uw2 = (const float*)d_in[24];
  const float* ub2 = (const float*)d_in[25];
  const float* bng = (const float*)d_in[26];
  const float* bnb = (const float*)d_in[27];
  float* out = (float*)d_out;

  char* Wc = (char*)d_ws;
  const size_t MB = 1u << 20;
  // dynamic regions (live-range reuse; see comments)
  u16*   A1    = (u16*)(Wc + 0 * MB);    // 6MB;  dead after src GEMM
  u16*   srcb  = (u16*)(Wc + 6 * MB);    // 8MB;  dead after QKV GEMM
  u16*   QKVb  = (u16*)(Wc + 14 * MB);   // 24MB; dead after attn
  u16*   aoInB = (u16*)(Wc + 38 * MB);   // 8MB;  dead after wo
  float* aoF   = (float*)(Wc + 46 * MB); // 16MB; read by ffn2 epilogue
  u16*   aoB   = (u16*)(Wc + 62 * MB);   // 8MB;  dead after ffn1
  u16*   h1B   = (u16*)(Wc + 70 * MB);   // 16MB; dead after ffn2
  float* xB    = (float*)(Wc + 14 * MB); // 16MB over dead QKVb; dead after LN
  u16*   yB    = (u16*)(Wc + 30 * MB);   // 8MB  over dead QKVb tail
  u16*   catB  = (u16*)(Wc + 0 * MB);    // 4MB  over dead A1
  u16*   tBb   = (u16*)(Wc + 4 * MB);    // 2MB  over dead A1 tail
  float* fB    = (float*)(Wc + 6 * MB);  // 4MB  over dead srcb

  // static weight area
  u16* qkvT  = (u16*)(Wc + 88 * MB);     // 768 x 256
  u16* woT   = qkvT + 196608;            // 256 x 256
  u16* fw1T  = woT + 65536;              // 512 x 256
  u16* fw2T  = fw1T + 131072;            // 256 x 512
  u16* W1T   = fw2T + 131072;            // 256 x 192
  u16* uw1T  = W1T + 49152;              // 64 x 256
  u16* uw2T  = uw1T + 16384;             // 64 x 128
  float* pbc = (float*)(uw2T + 8192);    // 256

  u32* cnt    = (u32*)(Wc + 90 * MB);
  u32* cursor = cnt + 16384;
  u32* startb = cnt + 32768;
  u32* pts    = cnt + 49152;
  int* idxb   = (int*)(cnt + 65536);     // N*16
  float* pS    = (float*)(cnt + 65536 + 262144);
  float* pQ    = pS + 8192;
  float* coefb = pQ + 8192;
  float* shb   = coefb + 64;

  hipMemsetAsync(cnt, 0, 32768 * sizeof(u32), stream);  // cnt + cursor

  k_hist<<<64, 256, 0, stream>>>(coords, cnt);
  k_scan<<<1, 256, 0, stream>>>(cnt, startb);
  k_scatter<<<64, 256, 0, stream>>>(coords, startb, cursor, pts);
  k_select<<<64, 256, 0, stream>>>(coords, startb, cnt, pts, idxb);

  WSet ws;
  ws.s[0] = wq;     ws.d[0] = qkvT;          ws.K[0] = 256; ws.N[0] = 256; ws.dstride[0] = 256; ws.coff[0] = 0;
  ws.s[1] = wk;     ws.d[1] = qkvT + 65536;  ws.K[1] = 256; ws.N[1] = 256; ws.dstride[1] = 256; ws.coff[1] = 0;
  ws.s[2] = wv;     ws.d[2] = qkvT + 131072; ws.K[2] = 256; ws.N[2] = 256; ws.dstride[2] = 256; ws.coff[2] = 0;
  ws.s[3] = wo;     ws.d[3] = woT;           ws.K[3] = 256; ws.N[3] = 256; ws.dstride[3] = 256; ws.coff[3] = 0;
  ws.s[4] = fw1;    ws.d[4] = fw1T;          ws.K[4] = 256; ws.N[4] = 512; ws.dstride[4] = 256; ws.coff[4] = 0;
  ws.s[5] = fw2;    ws.d[5] = fw2T;          ws.K[5] = 512; ws.N[5] = 256; ws.dstride[5] = 512; ws.coff[5] = 0;
  ws.s[6] = proj_w; ws.d[6] = W1T;           ws.K[6] = 64;  ws.N[6] = 256; ws.dstride[6] = 192; ws.coff[6] = 0;
  ws.s[7] = pe_w2;  ws.d[7] = W1T;           ws.K[7] = 128; ws.N[7] = 256; ws.dstride[7] = 192; ws.coff[7] = 64;
  ws.s[8] = uw1;    ws.d[8] = uw1T;          ws.K[8] = 256; ws.N[8] = 64;  ws.dstride[8] = 256; ws.coff[8] = 0;
  ws.s[9] = uw2;    ws.d[9] = uw2T;          ws.K[9] = 128; ws.N[9] = 64;  ws.dstride[9] = 128; ws.coff[9] = 0;
  k_wcast<<<dim3(128, 10), 256, 0, stream>>>(ws);
  k_bias2<<<1, 256, 0, stream>>>(proj_b, pe_b2, pbc);

  k_prep<<<512, 256, 0, stream>>>(coords, feats, pe_w1, pe_b1, A1);

  // src = A1 @ W1T^T + pbc  (bf16)
  k_mfma_gemm<0, 0, 1, 0><<<dim3(2, 128), 256, 0, stream>>>(A1, W1T, pbc, nullptr, srcb, nullptr, kN, 192, 256);
  // QKV fused (N=768)
  k_mfma_gemm<0, 0, 1, 0><<<dim3(6, 128), 256, 0, stream>>>(srcb, qkvT, nullptr, nullptr, QKVb, nullptr, kN, 256, 768);

  k_attn<<<512, 256, 0, stream>>>(QKVb, idxb, bq, bk, bv, aoInB);

  // ao = attn_out @ wo + bo  (fp32 for residual, bf16 for ffn1)
  k_mfma_gemm<0, 1, 1, 0><<<dim3(2, 128), 256, 0, stream>>>(aoInB, woT, bo, aoF, aoB, nullptr, kN, 256, 256);
  // h1 = relu(ao @ fw1 + fb1) (bf16)
  k_mfma_gemm<1, 0, 1, 0><<<dim3(4, 128), 256, 0, stream>>>(aoB, fw1T, fb1, nullptr, h1B, nullptr, kN, 256, 512);
  // x = ao + (h1 @ fw2 + fb2) (fp32, residual fused)
  k_mfma_gemm<0, 1, 0, 1><<<dim3(2, 128), 256, 0, stream>>>(h1B, fw2T, fb2, xB, nullptr, aoF, kN, 512, 256);

  k_ln<<<4096, 256, 0, stream>>>(xB, lng, lnb, yB);

  // t = y @ uw1 + ub1 (bf16, N=64)
  k_mfma_gemm<0, 0, 1, 0><<<dim3(1, 128), 256, 0, stream>>>(yB, uw1T, ub1, nullptr, tBb, nullptr, kN, 256, 64);
  k_cat<<<1024, 256, 0, stream>>>(feats, tBb, catB);
  // f = cat @ uw2 + ub2 (fp32, N=64)
  k_mfma_gemm<0, 1, 0, 0><<<dim3(1, 128), 256, 0, stream>>>(catB, uw2T, ub2, fB, nullptr, nullptr, kN, 128, 64);

  k_stats<<<128, 256, 0, stream>>>(fB, pS, pQ);
  k_bnfin<<<1, 64, 0, stream>>>(pS, pQ, bng, bnb, coefb, shb);
  k_bnapply<<<1024, 256, 0, stream>>>(fB, coefb, shb, out);
}

// Round 4
// 268.002 us; speedup vs baseline: 1.8803x; 1.0318x over previous
//
#include <hip/hip_runtime.h>
#include <stdint.h>

typedef unsigned short u16;
typedef unsigned int   u32;
typedef __attribute__((ext_vector_type(8))) short short8;
typedef __attribute__((ext_vector_type(4))) float f32x4;

static constexpr int kN = 16384;
static constexpr float kEPS = 1e-5f;

__device__ __forceinline__ u16 f2bf(float x) {
  u32 u = __float_as_uint(x);
  u32 r = (u + 0x7fffu + ((u >> 16) & 1u)) >> 16;
  return (u16)r;
}
__device__ __forceinline__ void ldbf8(const u16* p, float* o) {
  uint4 v = *(const uint4*)p;
  o[0] = __uint_as_float(v.x << 16);  o[1] = __uint_as_float(v.x & 0xffff0000u);
  o[2] = __uint_as_float(v.y << 16);  o[3] = __uint_as_float(v.y & 0xffff0000u);
  o[4] = __uint_as_float(v.z << 16);  o[5] = __uint_as_float(v.z & 0xffff0000u);
  o[6] = __uint_as_float(v.w << 16);  o[7] = __uint_as_float(v.w & 0xffff0000u);
}

// ---------------- neighbor grid (cells = x*128+y) ----------------

__global__ __launch_bounds__(256) void k_hist(const int* __restrict__ coords,
                                              u32* __restrict__ cnt) {
  int n = blockIdx.x * 256 + threadIdx.x;
  int c = coords[n * 3] * 128 + coords[n * 3 + 1];
  atomicAdd(&cnt[c], 1u);
}

__global__ __launch_bounds__(256) void k_scan(const u32* __restrict__ cnt,
                                              u32* __restrict__ startb) {
  __shared__ u32 tots[256];
  int t = threadIdx.x;
  int base = t * 64;
  u32 s = 0;
  for (int i = 0; i < 64; i++) s += cnt[base + i];
  tots[t] = s;
  __syncthreads();
  if (t == 0) {
    u32 run = 0;
    for (int i = 0; i < 256; i++) { u32 v = tots[i]; tots[i] = run; run += v; }
  }
  __syncthreads();
  u32 run = tots[t];
  for (int i = 0; i < 64; i++) { startb[base + i] = run; run += cnt[base + i]; }
}

__global__ __launch_bounds__(256) void k_scatter(const int* __restrict__ coords,
                                                 const u32* __restrict__ startb,
                                                 u32* __restrict__ cursor,
                                                 u32* __restrict__ pts) {
  int n = blockIdx.x * 256 + threadIdx.x;
  int x = coords[n * 3], y = coords[n * 3 + 1], z = coords[n * 3 + 2];
  int c = x * 128 + y;
  u32 slot = atomicAdd(&cursor[c], 1u);
  pts[startb[c] + slot] = ((u32)z << 14) | (u32)n;  // z:7b | idx:14b
}

__global__ __launch_bounds__(256) void k_select(const int* __restrict__ coords,
                                                const u32* __restrict__ startb,
                                                const u32* __restrict__ cnt,
                                                const u32* __restrict__ pts,
                                                int* __restrict__ idxo) {
  int n = blockIdx.x * 256 + threadIdx.x;
  int x = coords[n * 3], y = coords[n * 3 + 1], z = coords[n * 3 + 2];
  u32 best[16];
#pragma unroll
  for (int j = 0; j < 16; j++) best[j] = 0xFFFFFFFFu;
  const int dxs[13] = {0, -1, 1, 0, 0, -2, 2, 0, 0, -1, -1, 1, 1};
  const int dys[13] = {0, 0, 0, -1, 1, 0, 0, -2, 2, -1, 1, -1, 1};
  const int dbs[13] = {0, 1, 1, 1, 1, 2, 2, 2, 2, 2, 2, 2, 2};
#pragma unroll
  for (int t = 0; t < 13; t++) {
    int xx = x + dxs[t], yy = y + dys[t];
    if (xx < 0 || xx > 127 || yy < 0 || yy > 127) continue;
    int c = xx * 128 + yy;
    u32 s0 = startb[c], e0 = s0 + cnt[c];
    for (u32 i = s0; i < e0; ++i) {
      u32 p = pts[i];
      int zq = (int)(p >> 14);
      int id = (int)(p & 16383u);
      int az = z - zq; az = az < 0 ? -az : az;
      int dd = dbs[t] + az;
      u32 key = (dd <= 2) ? (((u32)dd << 14) | (u32)id) : 0xFFFFFFFFu;
#pragma unroll
      for (int j = 0; j < 16; j++) {
        u32 lo = min(best[j], key);
        u32 hi = max(best[j], key);
        best[j] = lo; key = hi;
      }
    }
  }
#pragma unroll
  for (int j = 0; j < 16; j++)
    idxo[n * 16 + j] = (best[j] == 0xFFFFFFFFu) ? -1 : (int)(best[j] & 16383u);
}

// ------- weight cast+transpose: S (K x N fp32) -> D[n*dstride+coff+k] -------
struct WSet {
  const float* s[8]; u16* d[8];
  int K[8]; int N[8]; int dstride[8]; int coff[8];
};

__global__ __launch_bounds__(256) void k_wcast(WSet ws) {
  int w = blockIdx.y;
  const float* S = ws.s[w]; u16* D = ws.d[w];
  int K = ws.K[w], N = ws.N[w], ds = ws.dstride[w], co = ws.coff[w];
  int ntx = N >> 5, tiles = ntx * (K >> 5);
  int t = blockIdx.x;
  if (t >= tiles) return;
  int n0 = (t % ntx) * 32, k0 = (t / ntx) * 32;
  __shared__ float st[32][33];
  int tr = threadIdx.x >> 3, tc4 = (threadIdx.x & 7) * 4;
  float4 v = *(const float4*)(S + (size_t)(k0 + tr) * N + n0 + tc4);
  st[tc4 + 0][tr] = v.x; st[tc4 + 1][tr] = v.y;
  st[tc4 + 2][tr] = v.z; st[tc4 + 3][tr] = v.w;
  __syncthreads();
  u16 o4[4];
  o4[0] = f2bf(st[tr][tc4 + 0]); o4[1] = f2bf(st[tr][tc4 + 1]);
  o4[2] = f2bf(st[tr][tc4 + 2]); o4[3] = f2bf(st[tr][tc4 + 3]);
  *(uint2*)(D + (size_t)(n0 + tr) * ds + co + k0 + tc4) = *(uint2*)o4;
}

// pbc = proj_b + pe_b2
__global__ __launch_bounds__(256) void k_bias2(const float* __restrict__ a,
                                               const float* __restrict__ b,
                                               float* __restrict__ o) {
  int t = threadIdx.x;
  o[t] = a[t] + b[t];
}

// fused tail weight: W2f[n][k<256] = (uw1 @ uw2[64:128])[k][n], W2f[n][256+c] = uw2[c][n]
// bbf[n] = ub2[n] + sum_j ub1[j]*uw2[64+j][n]
__global__ __launch_bounds__(320) void k_fuse2w(const float* __restrict__ uw1,
                                                const float* __restrict__ ub1,
                                                const float* __restrict__ uw2,
                                                const float* __restrict__ ub2,
                                                u16* __restrict__ W2f,
                                                float* __restrict__ bbf) {
  int n = blockIdx.x;   // 0..63
  int k = threadIdx.x;  // 0..319
  if (k < 256) {
    float s = 0.f;
    for (int j = 0; j < 64; j++) s += uw1[k * 64 + j] * uw2[(64 + j) * 64 + n];
    W2f[n * 320 + k] = f2bf(s);
  } else {
    W2f[n * 320 + k] = f2bf(uw2[(k - 256) * 64 + n]);
  }
  if (k == 0) {
    float s = ub2[n];
    for (int j = 0; j < 64; j++) s += ub1[j] * uw2[(64 + j) * 64 + n];
    bbf[n] = s;
  }
}

// ---------------- A1 = [features | relu(PE hidden)] bf16 N x 192;
//                  also A2[:,256:320] = features bf16 (stride 320) ----------------
__global__ __launch_bounds__(256) void k_prep(const int* __restrict__ coords,
                                              const float* __restrict__ feats,
                                              const float* __restrict__ pw1,
                                              const float* __restrict__ pb1,
                                              u16* __restrict__ A1,
                                              u16* __restrict__ A2) {
  int r0 = blockIdx.x * 32;
#pragma unroll
  for (int s = 0; s < 3; s++) {
    int j = threadIdx.x + s * 256;  // 0..767 = 32 rows x 24 segs
    int row = j / 24, seg = j % 24;
    int n = r0 + row;
    u16 o[8];
    if (seg < 8) {
      const float* fp = feats + (size_t)n * 64 + seg * 8;
      float4 a = *(const float4*)fp;
      float4 b = *(const float4*)(fp + 4);
      o[0] = f2bf(a.x); o[1] = f2bf(a.y); o[2] = f2bf(a.z); o[3] = f2bf(a.w);
      o[4] = f2bf(b.x); o[5] = f2bf(b.y); o[6] = f2bf(b.z); o[7] = f2bf(b.w);
      *(uint4*)(A2 + (size_t)n * 320 + 256 + seg * 8) = *(uint4*)o;
    } else {
      int jj0 = (seg - 8) * 8;
      float x0 = (float)coords[n * 3 + 0] * (1.f / 127.f);
      float x1 = (float)coords[n * 3 + 1] * (1.f / 127.f);
      float x2 = (float)coords[n * 3 + 2] * (1.f / 127.f);
#pragma unroll
      for (int u = 0; u < 8; u++) {
        int jj = jj0 + u;
        float hv = pb1[jj] + x0 * pw1[jj] + x1 * pw1[128 + jj] + x2 * pw1[256 + jj];
        o[u] = f2bf(fmaxf(hv, 0.f));
      }
    }
    *(uint4*)(A1 + (size_t)n * 192 + seg * 8) = *(uint4*)o;
  }
}

// ---------------- bf16 MFMA GEMM: C = A(MxK) @ WT(NxK)^T ----------------
template <int ACT, int SF32, int SBF16, int ADD>
__global__ __launch_bounds__(256) void k_mfma_gemm(
    const u16* __restrict__ A, const u16* __restrict__ WT,
    const float* __restrict__ bias,
    float* __restrict__ Cf, u16* __restrict__ Cb,
    const float* __restrict__ Addp,
    int M, int K, int N) {
  __shared__ __align__(16) u16 As[128 * 32];
  __shared__ __align__(16) u16 Bs[128 * 32];
  const int tid = threadIdx.x;
  const int wave = tid >> 6, lane = tid & 63;
  const int bm = blockIdx.y * 128, bn = blockIdx.x * 128;
  const int wr = (wave >> 1) * 64, wc = (wave & 1) * 64;

  f32x4 acc[4][4];
#pragma unroll
  for (int i = 0; i < 4; i++)
#pragma unroll
    for (int j = 0; j < 4; j++)
#pragma unroll
      for (int r = 0; r < 4; r++) acc[i][j][r] = 0.f;

  for (int k0 = 0; k0 < K; k0 += 32) {
#pragma unroll
    for (int i = 0; i < 2; i++) {
      int cb = i * 256 + wave * 64;   // wave-uniform chunk base (16B chunks)
      int c = cb + lane;
      int row = c >> 2, ko = (c & 3) * 8;
      int rowb = min(row, N - 1 - bn);  // clamp B row for N<tile
      __builtin_amdgcn_global_load_lds(
          (const __attribute__((address_space(1))) void*)(A + (size_t)(bm + row) * K + k0 + ko),
          (__attribute__((address_space(3))) void*)(As + (size_t)cb * 8), 16, 0, 0);
      __builtin_amdgcn_global_load_lds(
          (const __attribute__((address_space(1))) void*)(WT + (size_t)(bn + rowb) * K + k0 + ko),
          (__attribute__((address_space(3))) void*)(Bs + (size_t)cb * 8), 16, 0, 0);
    }
    __syncthreads();
    short8 af[4], bg[4];
#pragma unroll
    for (int i = 0; i < 4; i++)
      af[i] = *(const short8*)&As[(wr + i * 16 + (lane & 15)) * 32 + (lane >> 4) * 8];
#pragma unroll
    for (int j = 0; j < 4; j++)
      bg[j] = *(const short8*)&Bs[(wc + j * 16 + (lane & 15)) * 32 + (lane >> 4) * 8];
#pragma unroll
    for (int i = 0; i < 4; i++)
#pragma unroll
      for (int j = 0; j < 4; j++)
        acc[i][j] = __builtin_amdgcn_mfma_f32_16x16x32_bf16(af[i], bg[j], acc[i][j], 0, 0, 0);
    __syncthreads();
  }

#pragma unroll
  for (int j = 0; j < 4; j++) {
    int cc = bn + wc + j * 16 + (lane & 15);
    if (cc >= N) continue;
    float bval = bias ? bias[cc] : 0.f;
#pragma unroll
    for (int i = 0; i < 4; i++) {
      int rbase = bm + wr + i * 16 + (lane >> 4) * 4;
#pragma unroll
      for (int r = 0; r < 4; r++) {
        float v = acc[i][j][r] + bval;
        size_t o = (size_t)(rbase + r) * N + cc;
        if (ADD) v += Addp[o];
        if (ACT) v = fmaxf(v, 0.f);
        if (SF32) Cf[o] = v;
        if (SBF16) Cb[o] = f2bf(v);
      }
    }
  }
}

// ---------------- attention: one thread per (query, head), cell-sorted order ----------------
// QKV row i: [0,256)=Q, [256,512)=K, [512,768)=V. Query order = pts (cell-sorted)
// so a block's 32 queries share their neighbor set -> L2/L1 reuse.
__global__ __launch_bounds__(256) void k_attn(const u16* __restrict__ QKV,
                                              const u32* __restrict__ pts,
                                              const int* __restrict__ idx,
                                              const float* __restrict__ bq,
                                              const float* __restrict__ bk,
                                              const float* __restrict__ bv,
                                              u16* __restrict__ outp) {
  int gid = blockIdx.x * 256 + threadIdx.x;
  int n = (int)(pts[gid >> 3] & 16383u), h = gid & 7;
  const int* ip = idx + n * 16;
  const int hb = h * 32;
  float q[32];
  {
    int i0 = ip[0];  // slot0: dist 0 (self) — always valid
    const u16* qp = QKV + (size_t)i0 * 768 + hb;
#pragma unroll
    for (int j = 0; j < 32; j += 8) ldbf8(qp + j, &q[j]);
#pragma unroll
    for (int j = 0; j < 32; j++) q[j] += bq[hb + j];
  }
  float qbk = 0.f;
#pragma unroll
  for (int j = 0; j < 32; j++) qbk += q[j] * bk[hb + j];
  float s[16]; int ii[16];
#pragma unroll
  for (int m = 0; m < 16; m++) {
    int i = ip[m]; ii[m] = i;
    float d = qbk;
    if (i >= 0) {
      const u16* kp = QKV + (size_t)i * 768 + 256 + hb;
      float kv[32];
#pragma unroll
      for (int j = 0; j < 32; j += 8) ldbf8(kp + j, &kv[j]);
#pragma unroll
      for (int j = 0; j < 32; j++) d += q[j] * kv[j];
    }
    s[m] = d * 0.17677669529663689f;  // 1/sqrt(32)
  }
  float mx = s[0];
#pragma unroll
  for (int m = 1; m < 16; m++) mx = fmaxf(mx, s[m]);
  float sum = 0.f;
#pragma unroll
  for (int m = 0; m < 16; m++) { s[m] = __expf(s[m] - mx); sum += s[m]; }
  float inv = 1.f / sum;
  float o[32];
#pragma unroll
  for (int j = 0; j < 32; j++) o[j] = 0.f;
#pragma unroll
  for (int m = 0; m < 16; m++) {
    if (ii[m] >= 0) {
      const u16* vp = QKV + (size_t)ii[m] * 768 + 512 + hb;
      float vv[32];
#pragma unroll
      for (int j = 0; j < 32; j += 8) ldbf8(vp + j, &vv[j]);
#pragma unroll
      for (int j = 0; j < 32; j++) o[j] += s[m] * vv[j];
    }
  }
  u16* op = outp + (size_t)n * 256 + hb;
#pragma unroll
  for (int j = 0; j < 32; j += 8) {
    u16 tmp[8];
#pragma unroll
    for (int jj = 0; jj < 8; jj++) tmp[jj] = f2bf(o[j + jj] * inv + bv[hb + j + jj]);
    *(uint4*)(op + j) = *(uint4*)tmp;
  }
}

// ---------------- layernorm over D=256, one wave per row, bf16 -> A2[:,0:256] ----------------
__global__ __launch_bounds__(256) void k_ln(const float* __restrict__ xx,
                                            const float* __restrict__ g,
                                            const float* __restrict__ b,
                                            u16* __restrict__ A2) {
  int row = blockIdx.x * 4 + (threadIdx.x >> 6);
  int lane = threadIdx.x & 63;
  float4 a = *(const float4*)(xx + (size_t)row * 256 + lane * 4);
  float x0 = a.x, x1 = a.y, x2 = a.z, x3 = a.w;
  float sm = x0 + x1 + x2 + x3;
#pragma unroll
  for (int off = 1; off < 64; off <<= 1) sm += __shfl_xor(sm, off);
  float mu = sm * (1.f / 256.f);
  float d0 = x0 - mu, d1 = x1 - mu, d2 = x2 - mu, d3 = x3 - mu;
  float sq = d0 * d0 + d1 * d1 + d2 * d2 + d3 * d3;
#pragma unroll
  for (int off = 1; off < 64; off <<= 1) sq += __shfl_xor(sq, off);
  float rstd = rsqrtf(sq * (1.f / 256.f) + kEPS);
  float4 gv = *(const float4*)(g + lane * 4);
  float4 bv4 = *(const float4*)(b + lane * 4);
  u16 o[4];
  o[0] = f2bf(d0 * rstd * gv.x + bv4.x); o[1] = f2bf(d1 * rstd * gv.y + bv4.y);
  o[2] = f2bf(d2 * rstd * gv.z + bv4.z); o[3] = f2bf(d3 * rstd * gv.w + bv4.w);
  *(uint2*)(A2 + (size_t)row * 320 + lane * 4) = *(uint2*)o;
}

// ---------------- batchnorm ----------------
__global__ __launch_bounds__(256) void k_stats(const float* __restrict__ f,
                                               float* __restrict__ pS, float* __restrict__ pQ) {
  int col = threadIdx.x & 63, rc = threadIdx.x >> 6;
  int r0 = blockIdx.x * 128 + rc * 32;
  float s = 0.f, q = 0.f;
  for (int r = 0; r < 32; r++) {
    float v = f[(size_t)(r0 + r) * 64 + col];
    s += v; q += v * v;
  }
  __shared__ float ls[4][64], lq[4][64];
  ls[rc][col] = s; lq[rc][col] = q;
  __syncthreads();
  if (rc == 0) {
    s = ls[0][col] + ls[1][col] + ls[2][col] + ls[3][col];
    q = lq[0][col] + lq[1][col] + lq[2][col] + lq[3][col];
    pS[blockIdx.x * 64 + col] = s;
    pQ[blockIdx.x * 64 + col] = q;
  }
}

__global__ __launch_bounds__(64) void k_bnfin(const float* __restrict__ pS,
                                              const float* __restrict__ pQ,
                                              const float* __restrict__ g,
                                              const float* __restrict__ b,
                                              float* __restrict__ coef,
                                              float* __restrict__ shift) {
  int c = threadIdx.x;
  float s = 0.f, q = 0.f;
  for (int i = 0; i < 128; i++) { s += pS[i * 64 + c]; q += pQ[i * 64 + c]; }
  float mu = s * (1.f / 16384.f);
  float var = q * (1.f / 16384.f) - mu * mu;
  float cf = rsqrtf(var + kEPS) * g[c];
  coef[c] = cf;
  shift[c] = b[c] - mu * cf;
}

__global__ __launch_bounds__(256) void k_bnapply(const float* __restrict__ f,
                                                 const float* __restrict__ coef,
                                                 const float* __restrict__ shift,
                                                 float* __restrict__ out) {
  int gid = blockIdx.x * 256 + threadIdx.x;
  int e = gid * 4, col = e & 63;
  float4 v = *(const float4*)(f + e);
  float4 cf = *(const float4*)(coef + col);
  float4 sh = *(const float4*)(shift + col);
  float4 o;
  o.x = fmaxf(v.x * cf.x + sh.x, 0.f);
  o.y = fmaxf(v.y * cf.y + sh.y, 0.f);
  o.z = fmaxf(v.z * cf.z + sh.z, 0.f);
  o.w = fmaxf(v.w * cf.w + sh.w, 0.f);
  *(float4*)(out + e) = o;
}

// ---------------- launch ----------------
extern "C" void kernel_launch(void* const* d_in, const int* in_sizes, int n_in,
                              void* d_out, int out_size, void* d_ws, size_t ws_size,
                              hipStream_t stream) {
  (void)in_sizes; (void)n_in; (void)out_size; (void)ws_size;
  const int*   coords = (const int*)d_in[0];
  const float* feats  = (const float*)d_in[1];
  const float* pe_w1  = (const float*)d_in[2];
  const float* pe_b1  = (const float*)d_in[3];
  const float* pe_w2  = (const float*)d_in[4];
  const float* pe_b2  = (const float*)d_in[5];
  const float* proj_w = (const float*)d_in[6];
  const float* proj_b = (const float*)d_in[7];
  const float* wq  = (const float*)d_in[8];
  const float* bq  = (const float*)d_in[9];
  const float* wk  = (const float*)d_in[10];
  const float* bk  = (const float*)d_in[11];
  const float* wv  = (const float*)d_in[12];
  const float* bv  = (const float*)d_in[13];
  const float* wo  = (const float*)d_in[14];
  const float* bo  = (const float*)d_in[15];
  const float* fw1 = (const float*)d_in[16];
  const float* fb1 = (const float*)d_in[17];
  const float* fw2 = (const float*)d_in[18];
  const float* fb2 = (const float*)d_in[19];
  const float* lng = (const float*)d_in[20];
  const float* lnb = (const float*)d_in[21];
  const float* uw1 = (const float*)d_in[22];
  const float* ub1 = (const float*)d_in[23];
  const float* uw2 = (const float*)d_in[24];
  const float* ub2 = (const float*)d_in[25];
  const float* bng = (const float*)d_in[26];
  const float* bnb = (const float*)d_in[27];
  float* out = (float*)d_out;

  char* Wc = (char*)d_ws;
  const size_t MB = 1u << 20;
  // dynamic regions (live-range reuse)
  u16*   A1    = (u16*)(Wc + 0 * MB);    // 6MB;  dead after src GEMM
  u16*   srcb  = (u16*)(Wc + 6 * MB);    // 8MB;  dead after QKV GEMM
  u16*   QKVb  = (u16*)(Wc + 14 * MB);   // 24MB; dead after attn
  u16*   aoInB = (u16*)(Wc + 38 * MB);   // 8MB;  dead after wo
  float* aoF   = (float*)(Wc + 46 * MB); // 16MB; read by ffn2 epilogue
  u16*   aoB   = (u16*)(Wc + 62 * MB);   // 8MB;  dead after ffn1
  u16*   h1B   = (u16*)(Wc + 70 * MB);   // 16MB; dead after ffn2
  u16*   A2    = (u16*)(Wc + 86 * MB);   // 10MB; [y | feats] (prep->fGEMM)
  float* xB    = (float*)(Wc + 14 * MB); // 16MB over dead QKVb; dead after LN
  float* fB    = (float*)(Wc + 0 * MB);  // 4MB  over dead A1

  // static weight area
  u16* qkvT  = (u16*)(Wc + 96 * MB);     // 768 x 256
  u16* woT   = qkvT + 196608;            // 256 x 256
  u16* fw1T  = woT + 65536;              // 512 x 256
  u16* fw2T  = fw1T + 131072;            // 256 x 512
  u16* W1T   = fw2T + 131072;            // 256 x 192
  u16* W2f   = W1T + 49152;              // 64 x 320 (fused tail weight)
  float* pbc = (float*)(W2f + 20480);    // 256
  float* bbf = pbc + 256;                // 64

  u32* cnt    = (u32*)(Wc + 98 * MB);
  u32* cursor = cnt + 16384;
  u32* startb = cnt + 32768;
  u32* pts    = cnt + 49152;
  int* idxb   = (int*)(cnt + 65536);     // N*16
  float* pS    = (float*)(cnt + 65536 + 262144);
  float* pQ    = pS + 8192;
  float* coefb = pQ + 8192;
  float* shb   = coefb + 64;

  hipMemsetAsync(cnt, 0, 32768 * sizeof(u32), stream);  // cnt + cursor

  k_hist<<<64, 256, 0, stream>>>(coords, cnt);
  k_scan<<<1, 256, 0, stream>>>(cnt, startb);
  k_scatter<<<64, 256, 0, stream>>>(coords, startb, cursor, pts);
  k_select<<<64, 256, 0, stream>>>(coords, startb, cnt, pts, idxb);

  WSet ws;
  ws.s[0] = wq;     ws.d[0] = qkvT;          ws.K[0] = 256; ws.N[0] = 256; ws.dstride[0] = 256; ws.coff[0] = 0;
  ws.s[1] = wk;     ws.d[1] = qkvT + 65536;  ws.K[1] = 256; ws.N[1] = 256; ws.dstride[1] = 256; ws.coff[1] = 0;
  ws.s[2] = wv;     ws.d[2] = qkvT + 131072; ws.K[2] = 256; ws.N[2] = 256; ws.dstride[2] = 256; ws.coff[2] = 0;
  ws.s[3] = wo;     ws.d[3] = woT;           ws.K[3] = 256; ws.N[3] = 256; ws.dstride[3] = 256; ws.coff[3] = 0;
  ws.s[4] = fw1;    ws.d[4] = fw1T;          ws.K[4] = 256; ws.N[4] = 512; ws.dstride[4] = 256; ws.coff[4] = 0;
  ws.s[5] = fw2;    ws.d[5] = fw2T;          ws.K[5] = 512; ws.N[5] = 256; ws.dstride[5] = 512; ws.coff[5] = 0;
  ws.s[6] = proj_w; ws.d[6] = W1T;           ws.K[6] = 64;  ws.N[6] = 256; ws.dstride[6] = 192; ws.coff[6] = 0;
  ws.s[7] = pe_w2;  ws.d[7] = W1T;           ws.K[7] = 128; ws.N[7] = 256; ws.dstride[7] = 192; ws.coff[7] = 64;
  k_wcast<<<dim3(128, 8), 256, 0, stream>>>(ws);
  k_bias2<<<1, 256, 0, stream>>>(proj_b, pe_b2, pbc);
  k_fuse2w<<<64, 320, 0, stream>>>(uw1, ub1, uw2, ub2, W2f, bbf);

  k_prep<<<512, 256, 0, stream>>>(coords, feats, pe_w1, pe_b1, A1, A2);

  // src = A1 @ W1T^T + pbc  (bf16)
  k_mfma_gemm<0, 0, 1, 0><<<dim3(2, 128), 256, 0, stream>>>(A1, W1T, pbc, nullptr, srcb, nullptr, kN, 192, 256);
  // QKV fused (N=768)
  k_mfma_gemm<0, 0, 1, 0><<<dim3(6, 128), 256, 0, stream>>>(srcb, qkvT, nullptr, nullptr, QKVb, nullptr, kN, 256, 768);

  k_attn<<<512, 256, 0, stream>>>(QKVb, pts, idxb, bq, bk, bv, aoInB);

  // ao = attn_out @ wo + bo  (fp32 for residual, bf16 for ffn1)
  k_mfma_gemm<0, 1, 1, 0><<<dim3(2, 128), 256, 0, stream>>>(aoInB, woT, bo, aoF, aoB, nullptr, kN, 256, 256);
  // h1 = relu(ao @ fw1 + fb1) (bf16)
  k_mfma_gemm<1, 0, 1, 0><<<dim3(4, 128), 256, 0, stream>>>(aoB, fw1T, fb1, nullptr, h1B, nullptr, kN, 256, 512);
  // x = ao + (h1 @ fw2 + fb2) (fp32, residual fused)
  k_mfma_gemm<0, 1, 0, 1><<<dim3(2, 128), 256, 0, stream>>>(h1B, fw2T, fb2, xB, nullptr, aoF, kN, 512, 256);

  k_ln<<<4096, 256, 0, stream>>>(xB, lng, lnb, A2);

  // f = A2([y|feats]) @ W2f^T + bbf  (fp32, N=64)
  k_mfma_gemm<0, 1, 0, 0><<<dim3(1, 128), 256, 0, stream>>>(A2, W2f, bbf, fB, nullptr, nullptr, kN, 320, 64);

  k_stats<<<128, 256, 0, stream>>>(fB, pS, pQ);
  k_bnfin<<<1, 64, 0, stream>>>(pS, pQ, bng, bnb, coefb, shb);
  k_bnapply<<<1024, 256, 0, stream>>>(fB, coefb, shb, out);
}

// Round 5
// 257.559 us; speedup vs baseline: 1.9565x; 1.0405x over previous
//
#include <hip/hip_runtime.h>
#include <stdint.h>

typedef unsigned short u16;
typedef unsigned int   u32;
typedef __attribute__((ext_vector_type(8))) short short8;
typedef __attribute__((ext_vector_type(4))) float f32x4;

static constexpr int kN = 16384;
static constexpr float kEPS = 1e-5f;

__device__ __forceinline__ u16 f2bf(float x) {
  u32 u = __float_as_uint(x);
  u32 r = (u + 0x7fffu + ((u >> 16) & 1u)) >> 16;
  return (u16)r;
}
__device__ __forceinline__ float bf2f(u16 x) {
  return __uint_as_float(((u32)x) << 16);
}
__device__ __forceinline__ void ldbf8(const u16* p, float* o) {
  uint4 v = *(const uint4*)p;
  o[0] = __uint_as_float(v.x << 16);  o[1] = __uint_as_float(v.x & 0xffff0000u);
  o[2] = __uint_as_float(v.y << 16);  o[3] = __uint_as_float(v.y & 0xffff0000u);
  o[4] = __uint_as_float(v.z << 16);  o[5] = __uint_as_float(v.z & 0xffff0000u);
  o[6] = __uint_as_float(v.w << 16);  o[7] = __uint_as_float(v.w & 0xffff0000u);
}

// ---------------- neighbor grid (cells = x*128+y) ----------------

__global__ __launch_bounds__(256) void k_hist(const int* __restrict__ coords,
                                              u32* __restrict__ cnt) {
  int n = blockIdx.x * 256 + threadIdx.x;
  int c = coords[n * 3] * 128 + coords[n * 3 + 1];
  atomicAdd(&cnt[c], 1u);
}

__global__ __launch_bounds__(256) void k_scan(const u32* __restrict__ cnt,
                                              u32* __restrict__ startb) {
  __shared__ u32 tots[256];
  int t = threadIdx.x;
  int base = t * 64;
  u32 s = 0;
  for (int i = 0; i < 64; i++) s += cnt[base + i];
  tots[t] = s;
  __syncthreads();
  if (t == 0) {
    u32 run = 0;
    for (int i = 0; i < 256; i++) { u32 v = tots[i]; tots[i] = run; run += v; }
  }
  __syncthreads();
  u32 run = tots[t];
  for (int i = 0; i < 64; i++) { startb[base + i] = run; run += cnt[base + i]; }
}

__global__ __launch_bounds__(256) void k_scatter(const int* __restrict__ coords,
                                                 const u32* __restrict__ startb,
                                                 u32* __restrict__ cursor,
                                                 u32* __restrict__ pts) {
  int n = blockIdx.x * 256 + threadIdx.x;
  int x = coords[n * 3], y = coords[n * 3 + 1], z = coords[n * 3 + 2];
  int c = x * 128 + y;
  u32 slot = atomicAdd(&cursor[c], 1u);
  pts[startb[c] + slot] = ((u32)z << 14) | (u32)n;  // z:7b | idx:14b
}

__global__ __launch_bounds__(256) void k_select(const int* __restrict__ coords,
                                                const u32* __restrict__ startb,
                                                const u32* __restrict__ cnt,
                                                const u32* __restrict__ pts,
                                                int* __restrict__ idxo) {
  int n = blockIdx.x * 256 + threadIdx.x;
  int x = coords[n * 3], y = coords[n * 3 + 1], z = coords[n * 3 + 2];
  u32 best[16];
#pragma unroll
  for (int j = 0; j < 16; j++) best[j] = 0xFFFFFFFFu;
  const int dxs[13] = {0, -1, 1, 0, 0, -2, 2, 0, 0, -1, -1, 1, 1};
  const int dys[13] = {0, 0, 0, -1, 1, 0, 0, -2, 2, -1, 1, -1, 1};
  const int dbs[13] = {0, 1, 1, 1, 1, 2, 2, 2, 2, 2, 2, 2, 2};
#pragma unroll
  for (int t = 0; t < 13; t++) {
    int xx = x + dxs[t], yy = y + dys[t];
    if (xx < 0 || xx > 127 || yy < 0 || yy > 127) continue;
    int c = xx * 128 + yy;
    u32 s0 = startb[c], e0 = s0 + cnt[c];
    for (u32 i = s0; i < e0; ++i) {
      u32 p = pts[i];
      int zq = (int)(p >> 14);
      int id = (int)(p & 16383u);
      int az = z - zq; az = az < 0 ? -az : az;
      int dd = dbs[t] + az;
      u32 key = (dd <= 2) ? (((u32)dd << 14) | (u32)id) : 0xFFFFFFFFu;
#pragma unroll
      for (int j = 0; j < 16; j++) {
        u32 lo = min(best[j], key);
        u32 hi = max(best[j], key);
        best[j] = lo; key = hi;
      }
    }
  }
#pragma unroll
  for (int j = 0; j < 16; j++)
    idxo[n * 16 + j] = (best[j] == 0xFFFFFFFFu) ? -1 : (int)(best[j] & 16383u);
}

// ------- fused setup: zero grid counters | weight cast+transpose | biases | tail fuse -------
// y in [0,8): wcast entry y; y==8: zero cnt+cursor; y==9: x==0 -> pbc, x in [1,65) -> fuse2w row
struct WSet {
  const float* s[8]; u16* d[8];
  int K[8]; int N[8]; int dstride[8]; int coff[8];
};

__global__ __launch_bounds__(256) void k_setup(WSet ws,
                                               u32* __restrict__ zero_area,
                                               const float* __restrict__ proj_b,
                                               const float* __restrict__ pe_b2,
                                               float* __restrict__ pbc,
                                               const float* __restrict__ uw1,
                                               const float* __restrict__ ub1,
                                               const float* __restrict__ uw2,
                                               const float* __restrict__ ub2,
                                               u16* __restrict__ W2f,
                                               float* __restrict__ bbf) {
  int w = blockIdx.y;
  if (w == 8) {
    zero_area[blockIdx.x * 256 + threadIdx.x] = 0u;  // 128*256 = 32768 = cnt+cursor
    return;
  }
  if (w == 9) {
    int bx = blockIdx.x;
    if (bx == 0) {
      pbc[threadIdx.x] = proj_b[threadIdx.x] + pe_b2[threadIdx.x];
    } else if (bx < 65) {
      int n = bx - 1;          // 0..63
      int k = threadIdx.x;     // 0..255
      float s = 0.f;
      for (int j = 0; j < 64; j++) s += uw1[k * 64 + j] * uw2[(64 + j) * 64 + n];
      W2f[n * 320 + k] = f2bf(s);
      if (k < 64) W2f[n * 320 + 256 + k] = f2bf(uw2[k * 64 + n]);
      if (k == 0) {
        float b = ub2[n];
        for (int j = 0; j < 64; j++) b += ub1[j] * uw2[(64 + j) * 64 + n];
        bbf[n] = b;
      }
    }
    return;
  }
  const float* S = ws.s[w]; u16* D = ws.d[w];
  int K = ws.K[w], N = ws.N[w], ds = ws.dstride[w], co = ws.coff[w];
  int ntx = N >> 5, tiles = ntx * (K >> 5);
  int t = blockIdx.x;
  if (t >= tiles) return;
  int n0 = (t % ntx) * 32, k0 = (t / ntx) * 32;
  __shared__ float st[32][33];
  int tr = threadIdx.x >> 3, tc4 = (threadIdx.x & 7) * 4;
  float4 v = *(const float4*)(S + (size_t)(k0 + tr) * N + n0 + tc4);
  st[tc4 + 0][tr] = v.x; st[tc4 + 1][tr] = v.y;
  st[tc4 + 2][tr] = v.z; st[tc4 + 3][tr] = v.w;
  __syncthreads();
  u16 o4[4];
  o4[0] = f2bf(st[tr][tc4 + 0]); o4[1] = f2bf(st[tr][tc4 + 1]);
  o4[2] = f2bf(st[tr][tc4 + 2]); o4[3] = f2bf(st[tr][tc4 + 3]);
  *(uint2*)(D + (size_t)(n0 + tr) * ds + co + k0 + tc4) = *(uint2*)o4;
}

// ---------------- A1 = [features | relu(PE hidden)] bf16 N x 192;
//                  also A2[:,256:320] = features bf16 (stride 320) ----------------
__global__ __launch_bounds__(256) void k_prep(const int* __restrict__ coords,
                                              const float* __restrict__ feats,
                                              const float* __restrict__ pw1,
                                              const float* __restrict__ pb1,
                                              u16* __restrict__ A1,
                                              u16* __restrict__ A2) {
  int r0 = blockIdx.x * 32;
#pragma unroll
  for (int s = 0; s < 3; s++) {
    int j = threadIdx.x + s * 256;  // 0..767 = 32 rows x 24 segs
    int row = j / 24, seg = j % 24;
    int n = r0 + row;
    u16 o[8];
    if (seg < 8) {
      const float* fp = feats + (size_t)n * 64 + seg * 8;
      float4 a = *(const float4*)fp;
      float4 b = *(const float4*)(fp + 4);
      o[0] = f2bf(a.x); o[1] = f2bf(a.y); o[2] = f2bf(a.z); o[3] = f2bf(a.w);
      o[4] = f2bf(b.x); o[5] = f2bf(b.y); o[6] = f2bf(b.z); o[7] = f2bf(b.w);
      *(uint4*)(A2 + (size_t)n * 320 + 256 + seg * 8) = *(uint4*)o;
    } else {
      int jj0 = (seg - 8) * 8;
      float x0 = (float)coords[n * 3 + 0] * (1.f / 127.f);
      float x1 = (float)coords[n * 3 + 1] * (1.f / 127.f);
      float x2 = (float)coords[n * 3 + 2] * (1.f / 127.f);
#pragma unroll
      for (int u = 0; u < 8; u++) {
        int jj = jj0 + u;
        float hv = pb1[jj] + x0 * pw1[jj] + x1 * pw1[128 + jj] + x2 * pw1[256 + jj];
        o[u] = f2bf(fmaxf(hv, 0.f));
      }
    }
    *(uint4*)(A1 + (size_t)n * 192 + seg * 8) = *(uint4*)o;
  }
}

// ---------------- bf16 MFMA GEMM: C = A(MxK) @ WT(NxK)^T ----------------
// BM x BN tile (64 or 128 each), BK=32, 256 threads (4 waves 2x2).
// M,N multiples of tile; K multiple of 32. OUTBF: 1=bf16 store, 0=f32.
// ADD: += bf16 Addp (same MxN layout).
template <int BM, int BN, int ACT, int OUTBF, int ADD>
__global__ __launch_bounds__(256) void k_mfma_gemm(
    const u16* __restrict__ A, const u16* __restrict__ WT,
    const float* __restrict__ bias,
    void* __restrict__ Cout,
    const u16* __restrict__ Addp,
    int M, int K, int N) {
  constexpr int GA = BM / 64;        // A chunk-groups (256 x 16B each)
  constexpr int GT = (BM + BN) / 64; // total groups
  constexpr int AI = BM / 32;        // A frags / wave
  constexpr int BI = BN / 32;        // B frags / wave
  __shared__ __align__(16) u16 As[BM * 32];
  __shared__ __align__(16) u16 Bs[BN * 32];
  const int tid = threadIdx.x;
  const int wave = tid >> 6, lane = tid & 63;
  const int bm = blockIdx.y * BM, bn = blockIdx.x * BN;
  const int wr = (wave >> 1) * (BM / 2), wc = (wave & 1) * (BN / 2);

  f32x4 acc[AI][BI];
#pragma unroll
  for (int i = 0; i < AI; i++)
#pragma unroll
    for (int j = 0; j < BI; j++)
#pragma unroll
      for (int r = 0; r < 4; r++) acc[i][j][r] = 0.f;

  for (int k0 = 0; k0 < K; k0 += 32) {
#pragma unroll
    for (int i = 0; i < GT; i++) {
      int g = i * 256 + wave * 64 + lane;   // global 16B-chunk id
      if (i < GA) {
        int row = g >> 2, ko = (g & 3) * 8;
        __builtin_amdgcn_global_load_lds(
            (const __attribute__((address_space(1))) void*)(A + (size_t)(bm + row) * K + k0 + ko),
            (__attribute__((address_space(3))) void*)(As + (size_t)g * 8), 16, 0, 0);
      } else {
        int g2 = g - GA * 256;
        int row = g2 >> 2, ko = (g2 & 3) * 8;
        __builtin_amdgcn_global_load_lds(
            (const __attribute__((address_space(1))) void*)(WT + (size_t)(bn + row) * K + k0 + ko),
            (__attribute__((address_space(3))) void*)(Bs + (size_t)g2 * 8), 16, 0, 0);
      }
    }
    __syncthreads();
    short8 af[AI], bg[BI];
#pragma unroll
    for (int i = 0; i < AI; i++)
      af[i] = *(const short8*)&As[(wr + i * 16 + (lane & 15)) * 32 + (lane >> 4) * 8];
#pragma unroll
    for (int j = 0; j < BI; j++)
      bg[j] = *(const short8*)&Bs[(wc + j * 16 + (lane & 15)) * 32 + (lane >> 4) * 8];
#pragma unroll
    for (int i = 0; i < AI; i++)
#pragma unroll
      for (int j = 0; j < BI; j++)
        acc[i][j] = __builtin_amdgcn_mfma_f32_16x16x32_bf16(af[i], bg[j], acc[i][j], 0, 0, 0);
    __syncthreads();
  }

#pragma unroll
  for (int j = 0; j < BI; j++) {
    int cc = bn + wc + j * 16 + (lane & 15);
    float bval = bias ? bias[cc] : 0.f;
#pragma unroll
    for (int i = 0; i < AI; i++) {
      int rbase = bm + wr + i * 16 + (lane >> 4) * 4;
#pragma unroll
      for (int r = 0; r < 4; r++) {
        float v = acc[i][j][r] + bval;
        size_t o = (size_t)(rbase + r) * N + cc;
        if (ADD) v += bf2f(Addp[o]);
        if (ACT) v = fmaxf(v, 0.f);
        if (OUTBF) ((u16*)Cout)[o] = f2bf(v);
        else       ((float*)Cout)[o] = v;
      }
    }
  }
}

// ---------------- attention: one thread per (query, head), cell-sorted order ----------------
__global__ __launch_bounds__(256) void k_attn(const u16* __restrict__ QKV,
                                              const u32* __restrict__ pts,
                                              const int* __restrict__ idx,
                                              const float* __restrict__ bq,
                                              const float* __restrict__ bk,
                                              const float* __restrict__ bv,
                                              u16* __restrict__ outp) {
  int gid = blockIdx.x * 256 + threadIdx.x;
  int n = (int)(pts[gid >> 3] & 16383u), h = gid & 7;
  const int* ip = idx + n * 16;
  const int hb = h * 32;
  float q[32];
  {
    int i0 = ip[0];  // slot0: dist 0 (self) — always valid
    const u16* qp = QKV + (size_t)i0 * 768 + hb;
#pragma unroll
    for (int j = 0; j < 32; j += 8) ldbf8(qp + j, &q[j]);
#pragma unroll
    for (int j = 0; j < 32; j++) q[j] += bq[hb + j];
  }
  float qbk = 0.f;
#pragma unroll
  for (int j = 0; j < 32; j++) qbk += q[j] * bk[hb + j];
  float s[16]; int ii[16];
#pragma unroll
  for (int m = 0; m < 16; m++) {
    int i = ip[m]; ii[m] = i;
    float d = qbk;
    if (i >= 0) {
      const u16* kp = QKV + (size_t)i * 768 + 256 + hb;
      float kv[32];
#pragma unroll
      for (int j = 0; j < 32; j += 8) ldbf8(kp + j, &kv[j]);
#pragma unroll
      for (int j = 0; j < 32; j++) d += q[j] * kv[j];
    }
    s[m] = d * 0.17677669529663689f;  // 1/sqrt(32)
  }
  float mx = s[0];
#pragma unroll
  for (int m = 1; m < 16; m++) mx = fmaxf(mx, s[m]);
  float sum = 0.f;
#pragma unroll
  for (int m = 0; m < 16; m++) { s[m] = __expf(s[m] - mx); sum += s[m]; }
  float inv = 1.f / sum;
  float o[32];
#pragma unroll
  for (int j = 0; j < 32; j++) o[j] = 0.f;
#pragma unroll
  for (int m = 0; m < 16; m++) {
    if (ii[m] >= 0) {
      const u16* vp = QKV + (size_t)ii[m] * 768 + 512 + hb;
      float vv[32];
#pragma unroll
      for (int j = 0; j < 32; j += 8) ldbf8(vp + j, &vv[j]);
#pragma unroll
      for (int j = 0; j < 32; j++) o[j] += s[m] * vv[j];
    }
  }
  u16* op = outp + (size_t)n * 256 + hb;
#pragma unroll
  for (int j = 0; j < 32; j += 8) {
    u16 tmp[8];
#pragma unroll
    for (int jj = 0; jj < 8; jj++) tmp[jj] = f2bf(o[j + jj] * inv + bv[hb + j + jj]);
    *(uint4*)(op + j) = *(uint4*)tmp;
  }
}

// ---------------- layernorm over D=256 (bf16 in), one wave per row, bf16 -> A2[:,0:256] ----------------
__global__ __launch_bounds__(256) void k_ln(const u16* __restrict__ xx,
                                            const float* __restrict__ g,
                                            const float* __restrict__ b,
                                            u16* __restrict__ A2) {
  int row = blockIdx.x * 4 + (threadIdx.x >> 6);
  int lane = threadIdx.x & 63;
  uint2 raw = *(const uint2*)(xx + (size_t)row * 256 + lane * 4);
  float x0 = __uint_as_float(raw.x << 16), x1 = __uint_as_float(raw.x & 0xffff0000u);
  float x2 = __uint_as_float(raw.y << 16), x3 = __uint_as_float(raw.y & 0xffff0000u);
  float sm = x0 + x1 + x2 + x3;
#pragma unroll
  for (int off = 1; off < 64; off <<= 1) sm += __shfl_xor(sm, off);
  float mu = sm * (1.f / 256.f);
  float d0 = x0 - mu, d1 = x1 - mu, d2 = x2 - mu, d3 = x3 - mu;
  float sq = d0 * d0 + d1 * d1 + d2 * d2 + d3 * d3;
#pragma unroll
  for (int off = 1; off < 64; off <<= 1) sq += __shfl_xor(sq, off);
  float rstd = rsqrtf(sq * (1.f / 256.f) + kEPS);
  float4 gv = *(const float4*)(g + lane * 4);
  float4 bv4 = *(const float4*)(b + lane * 4);
  u16 o[4];
  o[0] = f2bf(d0 * rstd * gv.x + bv4.x); o[1] = f2bf(d1 * rstd * gv.y + bv4.y);
  o[2] = f2bf(d2 * rstd * gv.z + bv4.z); o[3] = f2bf(d3 * rstd * gv.w + bv4.w);
  *(uint2*)(A2 + (size_t)row * 320 + lane * 4) = *(uint2*)o;
}

// ---------------- batchnorm ----------------
__global__ __launch_bounds__(256) void k_stats(const float* __restrict__ f,
                                               float* __restrict__ pS, float* __restrict__ pQ) {
  int col = threadIdx.x & 63, rc = threadIdx.x >> 6;
  int r0 = blockIdx.x * 128 + rc * 32;
  float s = 0.f, q = 0.f;
  for (int r = 0; r < 32; r++) {
    float v = f[(size_t)(r0 + r) * 64 + col];
    s += v; q += v * v;
  }
  __shared__ float ls[4][64], lq[4][64];
  ls[rc][col] = s; lq[rc][col] = q;
  __syncthreads();
  if (rc == 0) {
    s = ls[0][col] + ls[1][col] + ls[2][col] + ls[3][col];
    q = lq[0][col] + lq[1][col] + lq[2][col] + lq[3][col];
    pS[blockIdx.x * 64 + col] = s;
    pQ[blockIdx.x * 64 + col] = q;
  }
}

__global__ __launch_bounds__(64) void k_bnfin(const float* __restrict__ pS,
                                              const float* __restrict__ pQ,
                                              const float* __restrict__ g,
                                              const float* __restrict__ b,
                                              float* __restrict__ coef,
                                              float* __restrict__ shift) {
  int c = threadIdx.x;
  float s = 0.f, q = 0.f;
  for (int i = 0; i < 128; i++) { s += pS[i * 64 + c]; q += pQ[i * 64 + c]; }
  float mu = s * (1.f / 16384.f);
  float var = q * (1.f / 16384.f) - mu * mu;
  float cf = rsqrtf(var + kEPS) * g[c];
  coef[c] = cf;
  shift[c] = b[c] - mu * cf;
}

__global__ __launch_bounds__(256) void k_bnapply(const float* __restrict__ f,
                                                 const float* __restrict__ coef,
                                                 const float* __restrict__ shift,
                                                 float* __restrict__ out) {
  int gid = blockIdx.x * 256 + threadIdx.x;
  int e = gid * 4, col = e & 63;
  float4 v = *(const float4*)(f + e);
  float4 cf = *(const float4*)(coef + col);
  float4 sh = *(const float4*)(shift + col);
  float4 o;
  o.x = fmaxf(v.x * cf.x + sh.x, 0.f);
  o.y = fmaxf(v.y * cf.y + sh.y, 0.f);
  o.z = fmaxf(v.z * cf.z + sh.z, 0.f);
  o.w = fmaxf(v.w * cf.w + sh.w, 0.f);
  *(float4*)(out + e) = o;
}

// ---------------- launch ----------------
extern "C" void kernel_launch(void* const* d_in, const int* in_sizes, int n_in,
                              void* d_out, int out_size, void* d_ws, size_t ws_size,
                              hipStream_t stream) {
  (void)in_sizes; (void)n_in; (void)out_size; (void)ws_size;
  const int*   coords = (const int*)d_in[0];
  const float* feats  = (const float*)d_in[1];
  const float* pe_w1  = (const float*)d_in[2];
  const float* pe_b1  = (const float*)d_in[3];
  const float* pe_w2  = (const float*)d_in[4];
  const float* pe_b2  = (const float*)d_in[5];
  const float* proj_w = (const float*)d_in[6];
  const float* proj_b = (const float*)d_in[7];
  const float* wq  = (const float*)d_in[8];
  const float* bq  = (const float*)d_in[9];
  const float* wk  = (const float*)d_in[10];
  const float* bk  = (const float*)d_in[11];
  const float* wv  = (const float*)d_in[12];
  const float* bv  = (const float*)d_in[13];
  const float* wo  = (const float*)d_in[14];
  const float* bo  = (const float*)d_in[15];
  const float* fw1 = (const float*)d_in[16];
  const float* fb1 = (const float*)d_in[17];
  const float* fw2 = (const float*)d_in[18];
  const float* fb2 = (const float*)d_in[19];
  const float* lng = (const float*)d_in[20];
  const float* lnb = (const float*)d_in[21];
  const float* uw1 = (const float*)d_in[22];
  const float* ub1 = (const float*)d_in[23];
  const float* uw2 = (const float*)d_in[24];
  const float* ub2 = (const float*)d_in[25];
  const float* bng = (const float*)d_in[26];
  const float* bnb = (const float*)d_in[27];
  float* out = (float*)d_out;

  char* Wc = (char*)d_ws;
  const size_t MB = 1u << 20;
  // dynamic regions (live-range reuse)
  u16*   A1    = (u16*)(Wc + 0 * MB);    // 6MB;  dead after src GEMM
  u16*   srcb  = (u16*)(Wc + 6 * MB);    // 8MB;  dead after QKV GEMM
  u16*   QKVb  = (u16*)(Wc + 14 * MB);   // 24MB; dead after attn
  u16*   aoInB = (u16*)(Wc + 38 * MB);   // 8MB;  dead after wo
  u16*   aoB   = (u16*)(Wc + 46 * MB);   // 8MB;  read by ffn1 + ffn2 epilogue
  u16*   h1B   = (u16*)(Wc + 54 * MB);   // 16MB; dead after ffn2
  u16*   xBb   = (u16*)(Wc + 70 * MB);   // 8MB;  dead after LN
  u16*   A2    = (u16*)(Wc + 78 * MB);   // 10MB; [y | feats] (prep->fGEMM)
  float* fB    = (float*)(Wc + 0 * MB);  // 4MB  over dead A1

  // static weight area
  u16* qkvT  = (u16*)(Wc + 96 * MB);     // 768 x 256
  u16* woT   = qkvT + 196608;            // 256 x 256
  u16* fw1T  = woT + 65536;              // 512 x 256
  u16* fw2T  = fw1T + 131072;            // 256 x 512
  u16* W1T   = fw2T + 131072;            // 256 x 192
  u16* W2f   = W1T + 49152;              // 64 x 320 (fused tail weight)
  float* pbc = (float*)(W2f + 20480);    // 256
  float* bbf = pbc + 256;                // 64

  u32* cnt    = (u32*)(Wc + 98 * MB);
  u32* cursor = cnt + 16384;
  u32* startb = cnt + 32768;
  u32* pts    = cnt + 49152;
  int* idxb   = (int*)(cnt + 65536);     // N*16
  float* pS    = (float*)(cnt + 65536 + 262144);
  float* pQ    = pS + 8192;
  float* coefb = pQ + 8192;
  float* shb   = coefb + 64;

  WSet ws;
  ws.s[0] = wq;     ws.d[0] = qkvT;          ws.K[0] = 256; ws.N[0] = 256; ws.dstride[0] = 256; ws.coff[0] = 0;
  ws.s[1] = wk;     ws.d[1] = qkvT + 65536;  ws.K[1] = 256; ws.N[1] = 256; ws.dstride[1] = 256; ws.coff[1] = 0;
  ws.s[2] = wv;     ws.d[2] = qkvT + 131072; ws.K[2] = 256; ws.N[2] = 256; ws.dstride[2] = 256; ws.coff[2] = 0;
  ws.s[3] = wo;     ws.d[3] = woT;           ws.K[3] = 256; ws.N[3] = 256; ws.dstride[3] = 256; ws.coff[3] = 0;
  ws.s[4] = fw1;    ws.d[4] = fw1T;          ws.K[4] = 256; ws.N[4] = 512; ws.dstride[4] = 256; ws.coff[4] = 0;
  ws.s[5] = fw2;    ws.d[5] = fw2T;          ws.K[5] = 512; ws.N[5] = 256; ws.dstride[5] = 512; ws.coff[5] = 0;
  ws.s[6] = proj_w; ws.d[6] = W1T;           ws.K[6] = 64;  ws.N[6] = 256; ws.dstride[6] = 192; ws.coff[6] = 0;
  ws.s[7] = pe_w2;  ws.d[7] = W1T;           ws.K[7] = 128; ws.N[7] = 256; ws.dstride[7] = 192; ws.coff[7] = 64;
  // setup: zeroes cnt+cursor (slice 8), weight casts (0-7), pbc+W2f/bbf (slice 9)
  k_setup<<<dim3(128, 10), 256, 0, stream>>>(ws, cnt, proj_b, pe_b2, pbc,
                                             uw1, ub1, uw2, ub2, W2f, bbf);

  k_hist<<<64, 256, 0, stream>>>(coords, cnt);
  k_scan<<<1, 256, 0, stream>>>(cnt, startb);
  k_scatter<<<64, 256, 0, stream>>>(coords, startb, cursor, pts);
  k_select<<<64, 256, 0, stream>>>(coords, startb, cnt, pts, idxb);

  k_prep<<<512, 256, 0, stream>>>(coords, feats, pe_w1, pe_b1, A1, A2);

  // src = A1 @ W1T^T + pbc  (bf16)
  k_mfma_gemm<64, 64, 0, 1, 0><<<dim3(4, 256), 256, 0, stream>>>(A1, W1T, pbc, srcb, nullptr, kN, 192, 256);
  // QKV fused (N=768)
  k_mfma_gemm<64, 64, 0, 1, 0><<<dim3(12, 256), 256, 0, stream>>>(srcb, qkvT, nullptr, QKVb, nullptr, kN, 256, 768);

  k_attn<<<512, 256, 0, stream>>>(QKVb, pts, idxb, bq, bk, bv, aoInB);

  // ao = attn_out @ wo + bo (bf16)
  k_mfma_gemm<64, 64, 0, 1, 0><<<dim3(4, 256), 256, 0, stream>>>(aoInB, woT, bo, aoB, nullptr, kN, 256, 256);
  // h1 = relu(ao @ fw1 + fb1) (bf16)
  k_mfma_gemm<64, 64, 1, 1, 0><<<dim3(8, 256), 256, 0, stream>>>(aoB, fw1T, fb1, h1B, nullptr, kN, 256, 512);
  // x = ao + (h1 @ fw2 + fb2) (bf16, residual fused from bf16 ao)
  k_mfma_gemm<64, 64, 0, 1, 1><<<dim3(4, 256), 256, 0, stream>>>(h1B, fw2T, fb2, xBb, aoB, kN, 512, 256);

  k_ln<<<4096, 256, 0, stream>>>(xBb, lng, lnb, A2);

  // f = A2([y|feats]) @ W2f^T + bbf  (fp32, N=64)
  k_mfma_gemm<64, 64, 0, 0, 0><<<dim3(1, 256), 256, 0, stream>>>(A2, W2f, bbf, fB, nullptr, kN, 320, 64);

  k_stats<<<128, 256, 0, stream>>>(fB, pS, pQ);
  k_bnfin<<<1, 64, 0, stream>>>(pS, pQ, bng, bnb, coefb, shb);
  k_bnapply<<<1024, 256, 0, stream>>>(fB, coefb, shb, out);
}